// Round 1
// baseline (925.816 us; speedup 1.0000x reference)
//
#include <hip/hip_runtime.h>

#define CN0 100000
#define CN1 50000
#define CN2 8000
#define CE0 600000
#define CE1 80000
#define CFIN 256
#define CHID 64
#define CNH 4
#define CNC 47
#define CHD1 256   // NH*HID
#define CHC2 188   // NH*NC

static __host__ __device__ inline int cdiv(int a, int b) { return (a + b - 1) / b; }

// ---------------- SGEMM: C[M,N] = A[M,K] @ B[K,N], f32, BM=BN=128, BK=8, 256 thr, 8x8/thr
__global__ __launch_bounds__(256) void sgemm_kernel(const float* __restrict__ A,
                                                    const float* __restrict__ B,
                                                    float* __restrict__ C,
                                                    int M, int N, int K) {
    __shared__ __align__(16) float As[8][128];
    __shared__ __align__(16) float Bs[8][128];
    int tid = threadIdx.x;
    int tx = tid & 15, ty = tid >> 4;
    int rowBase = blockIdx.x * 128;
    int colBase = blockIdx.y * 128;

    float acc[8][8];
#pragma unroll
    for (int i = 0; i < 8; i++)
#pragma unroll
        for (int j = 0; j < 8; j++) acc[i][j] = 0.f;

    int aRow = tid >> 1, aCol = (tid & 1) * 4;   // A tile: 128 rows x 8 cols
    int bRow = tid >> 5, bCol = (tid & 31) * 4;  // B tile: 8 rows x 128 cols

    for (int k0 = 0; k0 < K; k0 += 8) {
        // load A (transposed into LDS)
        float4 av = make_float4(0.f, 0.f, 0.f, 0.f);
        int gr = rowBase + aRow;
        if (gr < M) av = *reinterpret_cast<const float4*>(&A[(size_t)gr * K + k0 + aCol]);
        As[aCol + 0][aRow] = av.x;
        As[aCol + 1][aRow] = av.y;
        As[aCol + 2][aRow] = av.z;
        As[aCol + 3][aRow] = av.w;
        // load B
        int gc = colBase + bCol;
        float4 bv;
        if (gc + 3 < N) {
            bv = *reinterpret_cast<const float4*>(&B[(size_t)(k0 + bRow) * N + gc]);
        } else {
            float t0 = 0.f, t1 = 0.f, t2 = 0.f, t3 = 0.f;
            if (gc + 0 < N) t0 = B[(size_t)(k0 + bRow) * N + gc + 0];
            if (gc + 1 < N) t1 = B[(size_t)(k0 + bRow) * N + gc + 1];
            if (gc + 2 < N) t2 = B[(size_t)(k0 + bRow) * N + gc + 2];
            if (gc + 3 < N) t3 = B[(size_t)(k0 + bRow) * N + gc + 3];
            bv = make_float4(t0, t1, t2, t3);
        }
        *reinterpret_cast<float4*>(&Bs[bRow][bCol]) = bv;
        __syncthreads();

#pragma unroll
        for (int k = 0; k < 8; k++) {
            float a[8], b[8];
            *reinterpret_cast<float4*>(&a[0]) = *reinterpret_cast<const float4*>(&As[k][ty * 8]);
            *reinterpret_cast<float4*>(&a[4]) = *reinterpret_cast<const float4*>(&As[k][ty * 8 + 4]);
            *reinterpret_cast<float4*>(&b[0]) = *reinterpret_cast<const float4*>(&Bs[k][tx * 8]);
            *reinterpret_cast<float4*>(&b[4]) = *reinterpret_cast<const float4*>(&Bs[k][tx * 8 + 4]);
#pragma unroll
            for (int i = 0; i < 8; i++)
#pragma unroll
                for (int j = 0; j < 8; j++) acc[i][j] += a[i] * b[j];
        }
        __syncthreads();
    }

#pragma unroll
    for (int i = 0; i < 8; i++) {
        int r = rowBase + ty * 8 + i;
        if (r >= M) continue;
#pragma unroll
        for (int j = 0; j < 8; j += 4) {
            int c = colBase + tx * 8 + j;
            if (c + 3 < N) {
                *reinterpret_cast<float4*>(&C[(size_t)r * N + c]) =
                    make_float4(acc[i][j], acc[i][j + 1], acc[i][j + 2], acc[i][j + 3]);
            } else {
#pragma unroll
                for (int u = 0; u < 4; u++)
                    if (c + u < N) C[(size_t)r * N + c + u] = acc[i][j + u];
            }
        }
    }
}

// ---------------- scores layer1: el[n,h] = <feat[n,h,:], al[h,:]>, er for n<n_dst
__global__ __launch_bounds__(256) void scores1_kernel(const float* __restrict__ feat,
                                                      const float* __restrict__ al,
                                                      const float* __restrict__ ar,
                                                      float* __restrict__ el,
                                                      float* __restrict__ er, int n_dst) {
    int n = blockIdx.x;
    int tid = threadIdx.x;
    int h = tid >> 6, dd = tid & 63;
    float f = feat[(size_t)n * CHD1 + tid];
    float pl = f * al[h * CHID + dd];
    float pr = f * ar[h * CHID + dd];
#pragma unroll
    for (int off = 32; off > 0; off >>= 1) {
        pl += __shfl_down(pl, off);
        pr += __shfl_down(pr, off);
    }
    if (dd == 0) {
        el[n * CNH + h] = pl;
        if (n < n_dst) er[n * CNH + h] = pr;
    }
}

// ---------------- scores layer2 (188-wide rows, heads of 47)
__global__ __launch_bounds__(192) void scores2_kernel(const float* __restrict__ feat,
                                                      const float* __restrict__ al,
                                                      const float* __restrict__ ar,
                                                      float* __restrict__ el,
                                                      float* __restrict__ er, int n_dst) {
    int n = blockIdx.x;
    int tid = threadIdx.x;
    __shared__ float pl[CHC2], pr[CHC2];
    if (tid < CHC2) {
        float f = feat[(size_t)n * CHC2 + tid];
        pl[tid] = f * al[tid];
        pr[tid] = f * ar[tid];
    }
    __syncthreads();
    if (tid < CNH) {
        float sl = 0.f, sr = 0.f;
        for (int c = 0; c < CNC; c++) {
            sl += pl[tid * CNC + c];
            sr += pr[tid * CNC + c];
        }
        el[n * CNH + tid] = sl;
        if (n < n_dst) er[n * CNH + tid] = sr;
    }
}

// ---------------- CSR build
__global__ void hist_kernel(const int* __restrict__ dst, int* __restrict__ counts, int E) {
    int i = blockIdx.x * blockDim.x + threadIdx.x;
    if (i < E) atomicAdd(&counts[dst[i]], 1);
}

__global__ __launch_bounds__(1024) void scan_kernel(const int* __restrict__ counts,
                                                    int* __restrict__ rp, int n) {
    __shared__ int sm[1024];
    __shared__ int carry_sh;
    int tid = threadIdx.x;
    if (tid == 0) {
        carry_sh = 0;
        rp[0] = 0;
    }
    __syncthreads();
    for (int base = 0; base < n; base += 1024) {
        int v = (base + tid < n) ? counts[base + tid] : 0;
        sm[tid] = v;
        __syncthreads();
        for (int off = 1; off < 1024; off <<= 1) {
            int t = (tid >= off) ? sm[tid - off] : 0;
            __syncthreads();
            sm[tid] += t;
            __syncthreads();
        }
        if (base + tid < n) rp[base + tid + 1] = carry_sh + sm[tid];
        __syncthreads();
        if (tid == 0) carry_sh += sm[1023];
        __syncthreads();
    }
}

__global__ void scatter_kernel(const int* __restrict__ dst, int* __restrict__ cursor,
                               int* __restrict__ eids, int E) {
    int i = blockIdx.x * blockDim.x + threadIdx.x;
    if (i < E) {
        int p = atomicAdd(&cursor[dst[i]], 1);
        eids[p] = i;
    }
}

// ---------------- layer-1 aggregation: one block (256 thr) per dst node
__global__ __launch_bounds__(256) void agg1_kernel(const float* __restrict__ feat,
                                                   const float* __restrict__ el,
                                                   const float* __restrict__ er,
                                                   const int* __restrict__ rp,
                                                   const int* __restrict__ eids,
                                                   const int* __restrict__ srcIdx,
                                                   const float* __restrict__ bias,
                                                   float* __restrict__ h1) {
    int dstn = blockIdx.x;
    int tid = threadIdx.x;
    __shared__ float er_sh[CNH], m_sh[CNH], inv_sh[CNH];
    __shared__ float wm[4][CNH], ws_[4][CNH];
    if (tid < CNH) er_sh[tid] = er[dstn * CNH + tid];
    int begin = rp[dstn], end = rp[dstn + 1];
    __syncthreads();

    float pm[CNH], ps[CNH];
#pragma unroll
    for (int h = 0; h < CNH; h++) {
        pm[h] = -1e30f;
        ps[h] = 0.f;
    }
    for (int i = begin + tid; i < end; i += 256) {
        int s = srcIdx[eids[i]];
#pragma unroll
        for (int h = 0; h < CNH; h++) {
            float v = el[s * CNH + h] + er_sh[h];
            v = v > 0.f ? v : 0.2f * v;
            float nm = fmaxf(pm[h], v);
            ps[h] = ps[h] * __expf(pm[h] - nm) + __expf(v - nm);
            pm[h] = nm;
        }
    }
#pragma unroll
    for (int off = 32; off > 0; off >>= 1) {
#pragma unroll
        for (int h = 0; h < CNH; h++) {
            float om = __shfl_down(pm[h], off);
            float os = __shfl_down(ps[h], off);
            float nm = fmaxf(pm[h], om);
            ps[h] = ps[h] * __expf(pm[h] - nm) + os * __expf(om - nm);
            pm[h] = nm;
        }
    }
    int wave = tid >> 6, lane = tid & 63;
    if (lane == 0) {
#pragma unroll
        for (int h = 0; h < CNH; h++) {
            wm[wave][h] = pm[h];
            ws_[wave][h] = ps[h];
        }
    }
    __syncthreads();
    if (tid < CNH) {
        float m = -1e30f, s = 0.f;
        for (int w = 0; w < 4; w++) {
            float om = wm[w][tid], os = ws_[w][tid];
            float nm = fmaxf(m, om);
            s = s * __expf(m - nm) + os * __expf(om - nm);
            m = nm;
        }
        m_sh[tid] = m;
        inv_sh[tid] = s > 0.f ? 1.f / s : 0.f;
    }
    __syncthreads();

    int h = tid >> 6;
    float m = m_sh[h], inv = inv_sh[h], erh = er_sh[h];
    float acc = 0.f;
    for (int i = begin; i < end; i++) {
        int s = srcIdx[eids[i]];
        float v = el[s * CNH + h] + erh;
        v = v > 0.f ? v : 0.2f * v;
        float alpha = __expf(v - m) * inv;
        acc += alpha * feat[(size_t)s * CHD1 + tid];
    }
    float o = acc + bias[tid];
    h1[(size_t)dstn * CHD1 + tid] = o > 0.f ? o : expm1f(o);  // ELU
}

// ---------------- layer-2 aggregation: one block (192 thr) per dst node, fused head-mean
__global__ __launch_bounds__(192) void agg2_kernel(const float* __restrict__ feat,
                                                   const float* __restrict__ el,
                                                   const float* __restrict__ er,
                                                   const int* __restrict__ rp,
                                                   const int* __restrict__ eids,
                                                   const int* __restrict__ srcIdx,
                                                   const float* __restrict__ bias,
                                                   float* __restrict__ out) {
    int dstn = blockIdx.x;
    int tid = threadIdx.x;
    __shared__ float er_sh[CNH], m_sh[CNH], inv_sh[CNH];
    __shared__ float wm[3][CNH], ws_[3][CNH];
    __shared__ float osh[CHC2];
    if (tid < CNH) er_sh[tid] = er[dstn * CNH + tid];
    int begin = rp[dstn], end = rp[dstn + 1];
    __syncthreads();

    float pm[CNH], ps[CNH];
#pragma unroll
    for (int h = 0; h < CNH; h++) {
        pm[h] = -1e30f;
        ps[h] = 0.f;
    }
    for (int i = begin + tid; i < end; i += 192) {
        int s = srcIdx[eids[i]];
#pragma unroll
        for (int h = 0; h < CNH; h++) {
            float v = el[s * CNH + h] + er_sh[h];
            v = v > 0.f ? v : 0.2f * v;
            float nm = fmaxf(pm[h], v);
            ps[h] = ps[h] * __expf(pm[h] - nm) + __expf(v - nm);
            pm[h] = nm;
        }
    }
#pragma unroll
    for (int off = 32; off > 0; off >>= 1) {
#pragma unroll
        for (int h = 0; h < CNH; h++) {
            float om = __shfl_down(pm[h], off);
            float os = __shfl_down(ps[h], off);
            float nm = fmaxf(pm[h], om);
            ps[h] = ps[h] * __expf(pm[h] - nm) + os * __expf(om - nm);
            pm[h] = nm;
        }
    }
    int wave = tid >> 6, lane = tid & 63;
    if (lane == 0) {
#pragma unroll
        for (int h = 0; h < CNH; h++) {
            wm[wave][h] = pm[h];
            ws_[wave][h] = ps[h];
        }
    }
    __syncthreads();
    if (tid < CNH) {
        float m = -1e30f, s = 0.f;
        for (int w = 0; w < 3; w++) {
            float om = wm[w][tid], os = ws_[w][tid];
            float nm = fmaxf(m, om);
            s = s * __expf(m - nm) + os * __expf(om - nm);
            m = nm;
        }
        m_sh[tid] = m;
        inv_sh[tid] = s > 0.f ? 1.f / s : 0.f;
    }
    __syncthreads();

    if (tid < CHC2) {
        int h = tid / CNC;
        float m = m_sh[h], inv = inv_sh[h], erh = er_sh[h];
        float acc = 0.f;
        for (int i = begin; i < end; i++) {
            int s = srcIdx[eids[i]];
            float v = el[s * CNH + h] + erh;
            v = v > 0.f ? v : 0.2f * v;
            float alpha = __expf(v - m) * inv;
            acc += alpha * feat[(size_t)s * CHC2 + tid];
        }
        osh[tid] = acc + bias[tid];
    }
    __syncthreads();
    if (tid < CNC) {
        out[(size_t)dstn * CNC + tid] =
            0.25f * (osh[tid] + osh[CNC + tid] + osh[2 * CNC + tid] + osh[3 * CNC + tid]);
    }
}

extern "C" void kernel_launch(void* const* d_in, const int* in_sizes, int n_in,
                              void* d_out, int out_size, void* d_ws, size_t ws_size,
                              hipStream_t stream) {
    const float* x   = (const float*)d_in[0];
    const float* W1  = (const float*)d_in[1];
    const float* al1 = (const float*)d_in[2];
    const float* ar1 = (const float*)d_in[3];
    const float* b1  = (const float*)d_in[4];
    const float* W2  = (const float*)d_in[5];
    const float* al2 = (const float*)d_in[6];
    const float* ar2 = (const float*)d_in[7];
    const float* b2  = (const float*)d_in[8];
    const int* src0  = (const int*)d_in[9];
    const int* dst0  = (const int*)d_in[10];
    const int* src1  = (const int*)d_in[11];
    const int* dst1  = (const int*)d_in[12];
    float* out = (float*)d_out;

    // workspace carve (4B elements), 256B-aligned regions
    char* base = (char*)d_ws;
    size_t off = 0;
    auto carve = [&](size_t bytes) {
        void* p = base + off;
        off = (off + bytes + 255) & ~(size_t)255;
        return p;
    };
    float* feat1 = (float*)carve((size_t)CN0 * CHD1 * 4);  // 102.4 MB ; feat2 aliases
    float* h1    = (float*)carve((size_t)CN1 * CHD1 * 4);  // 51.2 MB
    float* el1   = (float*)carve((size_t)CN0 * CNH * 4);   // el2 aliases
    float* er1   = (float*)carve((size_t)CN1 * CNH * 4);   // er2 aliases
    int* rp0     = (int*)carve((CN1 + 1) * 4);
    int* cnt0    = (int*)carve(CN1 * 4);                   // counts then cursor
    int* eids0   = (int*)carve(CE0 * 4);
    int* rp1     = (int*)carve((CN2 + 1) * 4);
    int* cnt1    = (int*)carve(CN2 * 4);
    int* eids1   = (int*)carve(CE1 * 4);
    float* feat2 = feat1;  // [CN1, 188] <= feat1 region, feat1 dead after agg1
    float* el2 = el1;
    float* er2 = er1;

    // ---- CSR builds (independent of features)
    hipMemsetAsync(cnt0, 0, CN1 * 4, stream);
    hipMemsetAsync(cnt1, 0, CN2 * 4, stream);
    hist_kernel<<<cdiv(CE0, 256), 256, 0, stream>>>(dst0, cnt0, CE0);
    hist_kernel<<<cdiv(CE1, 256), 256, 0, stream>>>(dst1, cnt1, CE1);
    scan_kernel<<<1, 1024, 0, stream>>>(cnt0, rp0, CN1);
    scan_kernel<<<1, 1024, 0, stream>>>(cnt1, rp1, CN2);
    hipMemcpyAsync(cnt0, rp0, CN1 * 4, hipMemcpyDeviceToDevice, stream);
    hipMemcpyAsync(cnt1, rp1, CN2 * 4, hipMemcpyDeviceToDevice, stream);
    scatter_kernel<<<cdiv(CE0, 256), 256, 0, stream>>>(dst0, cnt0, eids0, CE0);
    scatter_kernel<<<cdiv(CE1, 256), 256, 0, stream>>>(dst1, cnt1, eids1, CE1);

    // ---- layer 1
    sgemm_kernel<<<dim3(cdiv(CN0, 128), cdiv(CHD1, 128)), 256, 0, stream>>>(
        x, W1, feat1, CN0, CHD1, CFIN);
    scores1_kernel<<<CN0, 256, 0, stream>>>(feat1, al1, ar1, el1, er1, CN1);
    agg1_kernel<<<CN1, 256, 0, stream>>>(feat1, el1, er1, rp0, eids0, src0, b1, h1);

    // ---- layer 2
    sgemm_kernel<<<dim3(cdiv(CN1, 128), cdiv(CHC2, 128)), 256, 0, stream>>>(
        h1, W2, feat2, CN1, CHC2, CHD1);
    scores2_kernel<<<CN1, 192, 0, stream>>>(feat2, al2, ar2, el2, er2, CN2);
    agg2_kernel<<<CN2, 192, 0, stream>>>(feat2, el2, er2, rp1, eids1, src1, b2, out);
}

// Round 2
// 759.022 us; speedup vs baseline: 1.2197x; 1.2197x over previous
//
#include <hip/hip_runtime.h>

#define CN0 100000
#define CN1 50000
#define CN2 8000
#define CE0 600000
#define CE1 80000
#define CFIN 256
#define CHID 64
#define CNH 4
#define CNC 47
#define CHD1 256   // NH*HID
#define CHC2 188   // NH*NC

static __host__ __device__ inline int cdiv(int a, int b) { return (a + b - 1) / b; }

// ---------------- SGEMM: C[M,N] = A[M,K] @ B[K,N], f32, BM=BN=128, BK=8, 256 thr, 8x8/thr
__global__ __launch_bounds__(256) void sgemm_kernel(const float* __restrict__ A,
                                                    const float* __restrict__ B,
                                                    float* __restrict__ C,
                                                    int M, int N, int K) {
    __shared__ __align__(16) float As[8][128];
    __shared__ __align__(16) float Bs[8][128];
    int tid = threadIdx.x;
    int tx = tid & 15, ty = tid >> 4;
    int rowBase = blockIdx.x * 128;
    int colBase = blockIdx.y * 128;

    float acc[8][8];
#pragma unroll
    for (int i = 0; i < 8; i++)
#pragma unroll
        for (int j = 0; j < 8; j++) acc[i][j] = 0.f;

    int aRow = tid >> 1, aCol = (tid & 1) * 4;   // A tile: 128 rows x 8 cols
    int bRow = tid >> 5, bCol = (tid & 31) * 4;  // B tile: 8 rows x 128 cols

    for (int k0 = 0; k0 < K; k0 += 8) {
        float4 av = make_float4(0.f, 0.f, 0.f, 0.f);
        int gr = rowBase + aRow;
        if (gr < M) av = *reinterpret_cast<const float4*>(&A[(size_t)gr * K + k0 + aCol]);
        As[aCol + 0][aRow] = av.x;
        As[aCol + 1][aRow] = av.y;
        As[aCol + 2][aRow] = av.z;
        As[aCol + 3][aRow] = av.w;
        int gc = colBase + bCol;
        float4 bv;
        if (gc + 3 < N) {
            bv = *reinterpret_cast<const float4*>(&B[(size_t)(k0 + bRow) * N + gc]);
        } else {
            float t0 = 0.f, t1 = 0.f, t2 = 0.f, t3 = 0.f;
            if (gc + 0 < N) t0 = B[(size_t)(k0 + bRow) * N + gc + 0];
            if (gc + 1 < N) t1 = B[(size_t)(k0 + bRow) * N + gc + 1];
            if (gc + 2 < N) t2 = B[(size_t)(k0 + bRow) * N + gc + 2];
            if (gc + 3 < N) t3 = B[(size_t)(k0 + bRow) * N + gc + 3];
            bv = make_float4(t0, t1, t2, t3);
        }
        *reinterpret_cast<float4*>(&Bs[bRow][bCol]) = bv;
        __syncthreads();

#pragma unroll
        for (int k = 0; k < 8; k++) {
            float a[8], b[8];
            *reinterpret_cast<float4*>(&a[0]) = *reinterpret_cast<const float4*>(&As[k][ty * 8]);
            *reinterpret_cast<float4*>(&a[4]) = *reinterpret_cast<const float4*>(&As[k][ty * 8 + 4]);
            *reinterpret_cast<float4*>(&b[0]) = *reinterpret_cast<const float4*>(&Bs[k][tx * 8]);
            *reinterpret_cast<float4*>(&b[4]) = *reinterpret_cast<const float4*>(&Bs[k][tx * 8 + 4]);
#pragma unroll
            for (int i = 0; i < 8; i++)
#pragma unroll
                for (int j = 0; j < 8; j++) acc[i][j] += a[i] * b[j];
        }
        __syncthreads();
    }

#pragma unroll
    for (int i = 0; i < 8; i++) {
        int r = rowBase + ty * 8 + i;
        if (r >= M) continue;
#pragma unroll
        for (int j = 0; j < 8; j += 4) {
            int c = colBase + tx * 8 + j;
            if (c + 3 < N) {
                *reinterpret_cast<float4*>(&C[(size_t)r * N + c]) =
                    make_float4(acc[i][j], acc[i][j + 1], acc[i][j + 2], acc[i][j + 3]);
            } else {
#pragma unroll
                for (int u = 0; u < 4; u++)
                    if (c + u < N) C[(size_t)r * N + c + u] = acc[i][j + u];
            }
        }
    }
}

// ---------------- scores layer1: el[n,h] = <feat[n,h,:], al[h,:]>, er for n<n_dst
__global__ __launch_bounds__(256) void scores1_kernel(const float* __restrict__ feat,
                                                      const float* __restrict__ al,
                                                      const float* __restrict__ ar,
                                                      float* __restrict__ el,
                                                      float* __restrict__ er, int n_dst) {
    int n = blockIdx.x;
    int tid = threadIdx.x;
    int h = tid >> 6, dd = tid & 63;
    float f = feat[(size_t)n * CHD1 + tid];
    float pl = f * al[h * CHID + dd];
    float pr = f * ar[h * CHID + dd];
#pragma unroll
    for (int off = 32; off > 0; off >>= 1) {
        pl += __shfl_down(pl, off);
        pr += __shfl_down(pr, off);
    }
    if (dd == 0) {
        el[n * CNH + h] = pl;
        if (n < n_dst) er[n * CNH + h] = pr;
    }
}

// ---------------- scores layer2 (188-wide rows, heads of 47)
__global__ __launch_bounds__(192) void scores2_kernel(const float* __restrict__ feat,
                                                      const float* __restrict__ al,
                                                      const float* __restrict__ ar,
                                                      float* __restrict__ el,
                                                      float* __restrict__ er, int n_dst) {
    int n = blockIdx.x;
    int tid = threadIdx.x;
    __shared__ float pl[CHC2], pr[CHC2];
    if (tid < CHC2) {
        float f = feat[(size_t)n * CHC2 + tid];
        pl[tid] = f * al[tid];
        pr[tid] = f * ar[tid];
    }
    __syncthreads();
    if (tid < CNH) {
        float sl = 0.f, sr = 0.f;
        for (int c = 0; c < CNC; c++) {
            sl += pl[tid * CNC + c];
            sr += pr[tid * CNC + c];
        }
        el[n * CNH + tid] = sl;
        if (n < n_dst) er[n * CNH + tid] = sr;
    }
}

// ---------------- CSR build
__global__ void hist_kernel(const int* __restrict__ dst, int* __restrict__ counts, int E) {
    int i = blockIdx.x * blockDim.x + threadIdx.x;
    if (i < E) atomicAdd(&counts[dst[i]], 1);
}

// 3-kernel scan: per-1024-chunk scan (256 thr x 4), chunk-sums scan, offset add.
__global__ __launch_bounds__(256) void scan1_kernel(const int* __restrict__ cnt,
                                                    int* __restrict__ rp,
                                                    int* __restrict__ bsums, int n) {
    __shared__ int sm[256];
    int b = blockIdx.x, tid = threadIdx.x;
    int base = b * 1024 + tid * 4;
    int v0 = 0, v1 = 0, v2 = 0, v3 = 0;
    if (base + 3 < n) {
        int4 q = *reinterpret_cast<const int4*>(&cnt[base]);
        v0 = q.x; v1 = q.y; v2 = q.z; v3 = q.w;
    } else {
        if (base + 0 < n) v0 = cnt[base + 0];
        if (base + 1 < n) v1 = cnt[base + 1];
        if (base + 2 < n) v2 = cnt[base + 2];
        if (base + 3 < n) v3 = cnt[base + 3];
    }
    int s1 = v0 + v1, s2 = s1 + v2, s3 = s2 + v3;
    sm[tid] = s3;
    __syncthreads();
    for (int off = 1; off < 256; off <<= 1) {
        int t = (tid >= off) ? sm[tid - off] : 0;
        __syncthreads();
        sm[tid] += t;
        __syncthreads();
    }
    int prefix = (tid > 0) ? sm[tid - 1] : 0;
    if (base + 0 < n) rp[base + 1] = prefix + v0;
    if (base + 1 < n) rp[base + 2] = prefix + s1;
    if (base + 2 < n) rp[base + 3] = prefix + s2;
    if (base + 3 < n) rp[base + 4] = prefix + s3;
    if (tid == 255) bsums[b] = sm[255];
    if (b == 0 && tid == 0) rp[0] = 0;
}

__global__ __launch_bounds__(256) void scan2_kernel(int* __restrict__ bsums, int nb) {
    __shared__ int sm[256];
    int tid = threadIdx.x;
    int v = (tid < nb) ? bsums[tid] : 0;
    sm[tid] = v;
    __syncthreads();
    for (int off = 1; off < 256; off <<= 1) {
        int t = (tid >= off) ? sm[tid - off] : 0;
        __syncthreads();
        sm[tid] += t;
        __syncthreads();
    }
    if (tid < nb) bsums[tid] = sm[tid] - v;  // exclusive
}

__global__ __launch_bounds__(256) void scan3_kernel(int* __restrict__ rp,
                                                    const int* __restrict__ bsums, int n) {
    int b = blockIdx.x, tid = threadIdx.x;
    if (b == 0) return;
    int add = bsums[b];
    int idx = b * 1024 + tid * 4;
#pragma unroll
    for (int u = 1; u <= 4; u++) {
        int p = idx + u;
        if (p <= n) rp[p] += add;
    }
}

// scatter: build CSR-ordered source index list directly (no eids indirection)
__global__ void scatter_kernel(const int* __restrict__ dst, const int* __restrict__ src,
                               int* __restrict__ cursor, int* __restrict__ csrsrc, int E) {
    int i = blockIdx.x * blockDim.x + threadIdx.x;
    if (i < E) {
        int p = atomicAdd(&cursor[dst[i]], 1);
        csrsrc[p] = src[i];
    }
}

// ---------------- per-edge alpha: one wave per dst node (4 waves/block)
__global__ __launch_bounds__(256) void alpha_kernel(const float* __restrict__ el,
                                                    const float* __restrict__ er,
                                                    const int* __restrict__ rp,
                                                    const int* __restrict__ csrsrc,
                                                    float* __restrict__ alpha, int n_dst) {
    int wid = (blockIdx.x * 256 + threadIdx.x) >> 6;
    int lane = threadIdx.x & 63;
    if (wid >= n_dst) return;
    int begin = rp[wid], end = rp[wid + 1];
    float4 erv = *reinterpret_cast<const float4*>(&er[wid * 4]);
    float m[4], s[4];
#pragma unroll
    for (int h = 0; h < 4; h++) { m[h] = -1e30f; s[h] = 0.f; }
    for (int i = begin + lane; i < end; i += 64) {
        int sn = csrsrc[i];
        float4 elv = *reinterpret_cast<const float4*>(&el[sn * 4]);
        float v[4] = {elv.x + erv.x, elv.y + erv.y, elv.z + erv.z, elv.w + erv.w};
#pragma unroll
        for (int h = 0; h < 4; h++) {
            float vv = v[h] > 0.f ? v[h] : 0.2f * v[h];
            float nm = fmaxf(m[h], vv);
            s[h] = s[h] * __expf(m[h] - nm) + __expf(vv - nm);
            m[h] = nm;
        }
    }
#pragma unroll
    for (int off = 1; off < 64; off <<= 1) {
#pragma unroll
        for (int h = 0; h < 4; h++) {
            float om = __shfl_xor(m[h], off);
            float os = __shfl_xor(s[h], off);
            float nm = fmaxf(m[h], om);
            s[h] = s[h] * __expf(m[h] - nm) + os * __expf(om - nm);
            m[h] = nm;
        }
    }
    float inv[4];
#pragma unroll
    for (int h = 0; h < 4; h++) inv[h] = s[h] > 0.f ? 1.f / s[h] : 0.f;
    for (int i = begin + lane; i < end; i += 64) {
        int sn = csrsrc[i];
        float4 elv = *reinterpret_cast<const float4*>(&el[sn * 4]);
        float v[4] = {elv.x + erv.x, elv.y + erv.y, elv.z + erv.z, elv.w + erv.w};
        float a[4];
#pragma unroll
        for (int h = 0; h < 4; h++) {
            float vv = v[h] > 0.f ? v[h] : 0.2f * v[h];
            a[h] = __expf(vv - m[h]) * inv[h];
        }
        *reinterpret_cast<float4*>(&alpha[(size_t)i * 4]) = make_float4(a[0], a[1], a[2], a[3]);
    }
}

// ---------------- layer-1 aggregation: block per dst, 4 waves x 4-edges-in-flight, float4
#define CHUNK 128
__global__ __launch_bounds__(256) void agg1_kernel(const float* __restrict__ feat,
                                                   const float* __restrict__ alpha,
                                                   const int* __restrict__ rp,
                                                   const int* __restrict__ csrsrc,
                                                   const float* __restrict__ bias,
                                                   float* __restrict__ h1) {
    int dstn = blockIdx.x;
    int tid = threadIdx.x;
    int wave = tid >> 6, lane = tid & 63;
    __shared__ int s_src[CHUNK];
    __shared__ __align__(16) float s_alpha[CHUNK][4];
    __shared__ __align__(16) float s_red[3][256];
    int begin = rp[dstn], end = rp[dstn + 1];
    int head = lane >> 4;  // lane covers features [4*lane, 4*lane+4) -> head = lane/16
    float4 acc = make_float4(0.f, 0.f, 0.f, 0.f);

    for (int cbase = begin; cbase < end; cbase += CHUNK) {
        int cn = min(end - cbase, CHUNK);
        for (int j = tid; j < cn; j += 256) {
            s_src[j] = csrsrc[cbase + j];
            *reinterpret_cast<float4*>(&s_alpha[j][0]) =
                *reinterpret_cast<const float4*>(&alpha[(size_t)(cbase + j) * 4]);
        }
        __syncthreads();
        for (int j = wave; j < cn; j += 4) {
            int sn = s_src[j];
            float a = s_alpha[j][head];
            float4 f = *reinterpret_cast<const float4*>(&feat[(size_t)sn * CHD1 + lane * 4]);
            acc.x += a * f.x; acc.y += a * f.y; acc.z += a * f.z; acc.w += a * f.w;
        }
        __syncthreads();
    }
    if (wave > 0) *reinterpret_cast<float4*>(&s_red[wave - 1][lane * 4]) = acc;
    __syncthreads();
    if (wave == 0) {
#pragma unroll
        for (int w = 0; w < 3; w++) {
            float4 o = *reinterpret_cast<float4*>(&s_red[w][lane * 4]);
            acc.x += o.x; acc.y += o.y; acc.z += o.z; acc.w += o.w;
        }
        float4 b = *reinterpret_cast<const float4*>(&bias[lane * 4]);
        float r[4] = {acc.x + b.x, acc.y + b.y, acc.z + b.z, acc.w + b.w};
#pragma unroll
        for (int u = 0; u < 4; u++) r[u] = r[u] > 0.f ? r[u] : expm1f(r[u]);  // ELU
        *reinterpret_cast<float4*>(&h1[(size_t)dstn * CHD1 + lane * 4]) =
            make_float4(r[0], r[1], r[2], r[3]);
    }
}

// ---------------- layer-2 aggregation: block per dst, 188 feats strided, fused head-mean
__global__ __launch_bounds__(256) void agg2_kernel(const float* __restrict__ feat,
                                                   const float* __restrict__ alpha,
                                                   const int* __restrict__ rp,
                                                   const int* __restrict__ csrsrc,
                                                   const float* __restrict__ bias,
                                                   float* __restrict__ out) {
    int dstn = blockIdx.x;
    int tid = threadIdx.x;
    int wave = tid >> 6, lane = tid & 63;
    __shared__ int s_src[CHUNK];
    __shared__ __align__(16) float s_alpha[CHUNK][4];
    __shared__ float s_red[3][192];
    __shared__ float s_out[192];
    int begin = rp[dstn], end = rp[dstn + 1];
    // lane covers features lane, lane+64, lane+128 (if < 188)
    int f0 = lane, f1 = lane + 64, f2 = lane + 128;
    int h0 = f0 / CNC, h1_ = f1 / CNC, h2 = f2 < CHC2 ? f2 / CNC : 3;
    float a0c = 0.f, a1c = 0.f, a2c = 0.f;

    for (int cbase = begin; cbase < end; cbase += CHUNK) {
        int cn = min(end - cbase, CHUNK);
        for (int j = tid; j < cn; j += 256) {
            s_src[j] = csrsrc[cbase + j];
            *reinterpret_cast<float4*>(&s_alpha[j][0]) =
                *reinterpret_cast<const float4*>(&alpha[(size_t)(cbase + j) * 4]);
        }
        __syncthreads();
        for (int j = wave; j < cn; j += 4) {
            int sn = s_src[j];
            const float* fr = &feat[(size_t)sn * CHC2];
            a0c += s_alpha[j][h0] * fr[f0];
            a1c += s_alpha[j][h1_] * fr[f1];
            if (f2 < CHC2) a2c += s_alpha[j][h2] * fr[f2];
        }
        __syncthreads();
    }
    if (wave > 0) {
        s_red[wave - 1][f0] = a0c;
        s_red[wave - 1][f1] = a1c;
        if (f2 < 192) s_red[wave - 1][f2] = a2c;
    }
    __syncthreads();
    if (wave == 0) {
#pragma unroll
        for (int w = 0; w < 3; w++) {
            a0c += s_red[w][f0];
            a1c += s_red[w][f1];
            if (f2 < 192) a2c += s_red[w][f2];
        }
        s_out[f0] = a0c + bias[f0];
        if (f1 < CHC2) s_out[f1] = a1c + bias[f1];
        if (f2 < CHC2) s_out[f2] = a2c + bias[f2];
    }
    __syncthreads();
    if (tid < CNC) {
        out[(size_t)dstn * CNC + tid] =
            0.25f * (s_out[tid] + s_out[CNC + tid] + s_out[2 * CNC + tid] + s_out[3 * CNC + tid]);
    }
}

extern "C" void kernel_launch(void* const* d_in, const int* in_sizes, int n_in,
                              void* d_out, int out_size, void* d_ws, size_t ws_size,
                              hipStream_t stream) {
    const float* x   = (const float*)d_in[0];
    const float* W1  = (const float*)d_in[1];
    const float* al1 = (const float*)d_in[2];
    const float* ar1 = (const float*)d_in[3];
    const float* b1  = (const float*)d_in[4];
    const float* W2  = (const float*)d_in[5];
    const float* al2 = (const float*)d_in[6];
    const float* ar2 = (const float*)d_in[7];
    const float* b2  = (const float*)d_in[8];
    const int* src0  = (const int*)d_in[9];
    const int* dst0  = (const int*)d_in[10];
    const int* src1  = (const int*)d_in[11];
    const int* dst1  = (const int*)d_in[12];
    float* out = (float*)d_out;

    char* base = (char*)d_ws;
    size_t off = 0;
    auto carve = [&](size_t bytes) {
        void* p = base + off;
        off = (off + bytes + 255) & ~(size_t)255;
        return p;
    };
    float* feat1   = (float*)carve((size_t)CN0 * CHD1 * 4);  // 102.4 MB; feat2 aliases
    float* h1      = (float*)carve((size_t)CN1 * CHD1 * 4);  // 51.2 MB
    float* el1     = (float*)carve((size_t)CN0 * CNH * 4);   // el2 aliases
    float* er1     = (float*)carve((size_t)CN1 * CNH * 4);   // er2 aliases
    int* rp0       = (int*)carve((CN1 + 1) * 4);
    int* cnt0      = (int*)carve(CN1 * 4);
    int* csrsrc0   = (int*)carve((size_t)CE0 * 4);
    float* alpha0  = (float*)carve((size_t)CE0 * CNH * 4);   // 9.6 MB
    int* rp1       = (int*)carve((CN2 + 1) * 4);
    int* cnt1      = (int*)carve(CN2 * 4);
    int* csrsrc1   = (int*)carve((size_t)CE1 * 4);
    float* alpha1  = (float*)carve((size_t)CE1 * CNH * 4);
    int* bsums0    = (int*)carve(64 * 4);
    int* bsums1    = (int*)carve(64 * 4);
    float* feat2 = feat1;  // feat1 dead after agg1
    float* el2 = el1;
    float* er2 = er1;

    // ---- CSR builds
    hipMemsetAsync(cnt0, 0, CN1 * 4, stream);
    hipMemsetAsync(cnt1, 0, CN2 * 4, stream);
    hist_kernel<<<cdiv(CE0, 256), 256, 0, stream>>>(dst0, cnt0, CE0);
    hist_kernel<<<cdiv(CE1, 256), 256, 0, stream>>>(dst1, cnt1, CE1);
    int nb0 = cdiv(CN1, 1024), nb1 = cdiv(CN2, 1024);
    scan1_kernel<<<nb0, 256, 0, stream>>>(cnt0, rp0, bsums0, CN1);
    scan1_kernel<<<nb1, 256, 0, stream>>>(cnt1, rp1, bsums1, CN2);
    scan2_kernel<<<1, 256, 0, stream>>>(bsums0, nb0);
    scan2_kernel<<<1, 256, 0, stream>>>(bsums1, nb1);
    scan3_kernel<<<nb0, 256, 0, stream>>>(rp0, bsums0, CN1);
    scan3_kernel<<<nb1, 256, 0, stream>>>(rp1, bsums1, CN2);
    hipMemcpyAsync(cnt0, rp0, CN1 * 4, hipMemcpyDeviceToDevice, stream);
    hipMemcpyAsync(cnt1, rp1, CN2 * 4, hipMemcpyDeviceToDevice, stream);
    scatter_kernel<<<cdiv(CE0, 256), 256, 0, stream>>>(dst0, src0, cnt0, csrsrc0, CE0);
    scatter_kernel<<<cdiv(CE1, 256), 256, 0, stream>>>(dst1, src1, cnt1, csrsrc1, CE1);

    // ---- layer 1
    sgemm_kernel<<<dim3(cdiv(CN0, 128), cdiv(CHD1, 128)), 256, 0, stream>>>(
        x, W1, feat1, CN0, CHD1, CFIN);
    scores1_kernel<<<CN0, 256, 0, stream>>>(feat1, al1, ar1, el1, er1, CN1);
    alpha_kernel<<<cdiv(CN1, 4), 256, 0, stream>>>(el1, er1, rp0, csrsrc0, alpha0, CN1);
    agg1_kernel<<<CN1, 256, 0, stream>>>(feat1, alpha0, rp0, csrsrc0, b1, h1);

    // ---- layer 2
    sgemm_kernel<<<dim3(cdiv(CN1, 128), cdiv(CHC2, 128)), 256, 0, stream>>>(
        h1, W2, feat2, CN1, CHC2, CHD1);
    scores2_kernel<<<CN1, 192, 0, stream>>>(feat2, al2, ar2, el2, er2, CN2);
    alpha_kernel<<<cdiv(CN2, 4), 256, 0, stream>>>(el2, er2, rp1, csrsrc1, alpha1, CN2);
    agg2_kernel<<<CN2, 256, 0, stream>>>(feat2, alpha1, rp1, csrsrc1, b2, out);
}

// Round 4
// 571.373 us; speedup vs baseline: 1.6203x; 1.3284x over previous
//
#include <hip/hip_runtime.h>

#define CN0 100000
#define CN1 50000
#define CN2 8000
#define CE0 600000
#define CE1 80000
#define CFIN 256
#define CHID 64
#define CNH 4
#define CNC 47
#define CHD1 256   // NH*HID
#define CHC2 188   // NH*NC

static __host__ __device__ inline int cdiv(int a, int b) { return (a + b - 1) / b; }

typedef __bf16 bf16x8 __attribute__((ext_vector_type(8)));
typedef __bf16 bf16x4 __attribute__((ext_vector_type(4)));
typedef float f32x16 __attribute__((ext_vector_type(16)));

// ---------------- W prep: W[K][N] f32 -> WT_hi[N][K], WT_lo[N][K] bf16 (transposed, split)
// K must be 256 (shifts hardcoded).
__global__ __launch_bounds__(256) void prep_w_kernel(const float* __restrict__ W,
                                                     __bf16* __restrict__ WTh,
                                                     __bf16* __restrict__ WTl, int N) {
    int id = blockIdx.x * 256 + threadIdx.x;
    if (id >= N * 256) return;
    int n = id >> 8, k = id & 255;
    float w = W[(size_t)k * N + n];
    __bf16 h = (__bf16)w;
    WTh[id] = h;
    WTl[id] = (__bf16)(w - (float)h);
}

// ---------------- split-bf16 MFMA GEMM: C[M,N] = A[M,K] @ B[K,N], f32 in/out.
// A split to hi/lo in-kernel; B pre-split as BT_hi/BT_lo [N][K] bf16.
// Block 128x128, BK=32, 4 waves, wave tile 64x64 = 2x2 frags of 32x32x16.
#define KP 40  // padded LDS k-stride (bf16): 80B rows, 16B-aligned, spreads banks
__global__ __launch_bounds__(256) void gemm_mfma_kernel(const float* __restrict__ A,
                                                        const __bf16* __restrict__ BTh,
                                                        const __bf16* __restrict__ BTl,
                                                        float* __restrict__ C,
                                                        int M, int N, int K) {
    __shared__ __align__(16) __bf16 Ah[128 * KP];
    __shared__ __align__(16) __bf16 Al[128 * KP];
    __shared__ __align__(16) __bf16 Bh[128 * KP];
    __shared__ __align__(16) __bf16 Bl[128 * KP];
    int tid = threadIdx.x;
    int wave = tid >> 6, lane = tid & 63;
    int rowBase = blockIdx.x * 128, colBase = blockIdx.y * 128;
    int wr = wave >> 1, wc = wave & 1;

    f32x16 acc[2][2];
#pragma unroll
    for (int m = 0; m < 2; m++)
#pragma unroll
        for (int n = 0; n < 2; n++)
#pragma unroll
            for (int r = 0; r < 16; r++) acc[m][n][r] = 0.f;

    // staging roles
    int arow = tid >> 1;          // 0..127
    int akc = (tid & 1) * 16;     // 0 or 16
    int bcol = tid & 127;         // 0..127
    int bsel = tid >> 7;          // 0 -> hi, 1 -> lo
    bool avalid = (rowBase + arow) < M;
    const float* aptr = &A[(size_t)(rowBase + arow) * K + akc];
    int gcol = colBase + bcol;
    const __bf16* bptr = (bsel ? BTl : BTh) + (size_t)gcol * K;
    __bf16* bdst = (bsel ? Bl : Bh) + bcol * KP;

    int rc = lane & 31;
    int kb = (lane >> 5) * 8;     // 0 or 8

    for (int k0 = 0; k0 < K; k0 += 32) {
        // ---- stage A: 128x32 f32 -> hi/lo bf16 (16 floats/thread)
#pragma unroll
        for (int c = 0; c < 4; c++) {
            float4 v = avalid ? *reinterpret_cast<const float4*>(aptr + k0 + c * 4)
                              : make_float4(0.f, 0.f, 0.f, 0.f);
            __bf16 h0 = (__bf16)v.x, h1 = (__bf16)v.y, h2 = (__bf16)v.z, h3 = (__bf16)v.w;
            bf16x4 hv = {h0, h1, h2, h3};
            bf16x4 lv = {(__bf16)(v.x - (float)h0), (__bf16)(v.y - (float)h1),
                         (__bf16)(v.z - (float)h2), (__bf16)(v.w - (float)h3)};
            int o = arow * KP + akc + c * 4;
            *reinterpret_cast<bf16x4*>(&Ah[o]) = hv;
            *reinterpret_cast<bf16x4*>(&Al[o]) = lv;
        }
        // ---- stage B: copy pre-split bf16 (32 bf16/thread for hi or lo)
        if (gcol < N) {
#pragma unroll
            for (int c = 0; c < 4; c++) {
                bf16x8 v = *reinterpret_cast<const bf16x8*>(&bptr[k0 + c * 8]);
                *reinterpret_cast<bf16x8*>(&bdst[c * 8]) = v;
            }
        } else {
#pragma unroll
            for (int c = 0; c < 4; c++) {
                bf16x8 z = {};
                *reinterpret_cast<bf16x8*>(&bdst[c * 8]) = z;
            }
        }
        __syncthreads();

        // ---- compute: 2 k-steps of 16, 2x2 frags, 3-term split = 24 MFMA
#pragma unroll
        for (int ks = 0; ks < 32; ks += 16) {
            bf16x8 fah[2], fal[2], fbh[2], fbl[2];
#pragma unroll
            for (int m = 0; m < 2; m++) {
                int r = wr * 64 + m * 32 + rc;
                fah[m] = *reinterpret_cast<const bf16x8*>(&Ah[r * KP + ks + kb]);
                fal[m] = *reinterpret_cast<const bf16x8*>(&Al[r * KP + ks + kb]);
            }
#pragma unroll
            for (int n = 0; n < 2; n++) {
                int cL = wc * 64 + n * 32 + rc;
                fbh[n] = *reinterpret_cast<const bf16x8*>(&Bh[cL * KP + ks + kb]);
                fbl[n] = *reinterpret_cast<const bf16x8*>(&Bl[cL * KP + ks + kb]);
            }
#pragma unroll
            for (int m = 0; m < 2; m++)
#pragma unroll
                for (int n = 0; n < 2; n++) {
                    acc[m][n] = __builtin_amdgcn_mfma_f32_32x32x16_bf16(fah[m], fbh[n],
                                                                        acc[m][n], 0, 0, 0);
                    acc[m][n] = __builtin_amdgcn_mfma_f32_32x32x16_bf16(fah[m], fbl[n],
                                                                        acc[m][n], 0, 0, 0);
                    acc[m][n] = __builtin_amdgcn_mfma_f32_32x32x16_bf16(fal[m], fbh[n],
                                                                        acc[m][n], 0, 0, 0);
                }
        }
        __syncthreads();
    }

    // ---- epilogue: D layout col=lane&31, row=(r&3)+8*(r>>2)+4*(lane>>5)
#pragma unroll
    for (int m = 0; m < 2; m++)
#pragma unroll
        for (int n = 0; n < 2; n++) {
            int col = colBase + wc * 64 + n * 32 + rc;
            if (col >= N) continue;
            int rbase = rowBase + wr * 64 + m * 32 + 4 * (lane >> 5);
#pragma unroll
            for (int r = 0; r < 16; r++) {
                int row = rbase + (r & 3) + 8 * (r >> 2);
                if (row < M) C[(size_t)row * N + col] = acc[m][n][r];
            }
        }
}

// ---------------- scores layer1: el[n,h] = <feat[n,h,:], al[h,:]>, er for n<n_dst
__global__ __launch_bounds__(256) void scores1_kernel(const float* __restrict__ feat,
                                                      const float* __restrict__ al,
                                                      const float* __restrict__ ar,
                                                      float* __restrict__ el,
                                                      float* __restrict__ er, int n_dst) {
    int n = blockIdx.x;
    int tid = threadIdx.x;
    int h = tid >> 6, dd = tid & 63;
    float f = feat[(size_t)n * CHD1 + tid];
    float pl = f * al[h * CHID + dd];
    float pr = f * ar[h * CHID + dd];
#pragma unroll
    for (int off = 32; off > 0; off >>= 1) {
        pl += __shfl_down(pl, off);
        pr += __shfl_down(pr, off);
    }
    if (dd == 0) {
        el[n * CNH + h] = pl;
        if (n < n_dst) er[n * CNH + h] = pr;
    }
}

// ---------------- scores layer2 (188-wide rows, heads of 47)
__global__ __launch_bounds__(192) void scores2_kernel(const float* __restrict__ feat,
                                                      const float* __restrict__ al,
                                                      const float* __restrict__ ar,
                                                      float* __restrict__ el,
                                                      float* __restrict__ er, int n_dst) {
    int n = blockIdx.x;
    int tid = threadIdx.x;
    __shared__ float pl[CHC2], pr[CHC2];
    if (tid < CHC2) {
        float f = feat[(size_t)n * CHC2 + tid];
        pl[tid] = f * al[tid];
        pr[tid] = f * ar[tid];
    }
    __syncthreads();
    if (tid < CNH) {
        float sl = 0.f, sr = 0.f;
        for (int c = 0; c < CNC; c++) {
            sl += pl[tid * CNC + c];
            sr += pr[tid * CNC + c];
        }
        el[n * CNH + tid] = sl;
        if (n < n_dst) er[n * CNH + tid] = sr;
    }
}

// ---------------- CSR build
__global__ void hist_kernel(const int* __restrict__ dst, int* __restrict__ counts, int E) {
    int i = blockIdx.x * blockDim.x + threadIdx.x;
    if (i < E) atomicAdd(&counts[dst[i]], 1);
}

__global__ __launch_bounds__(256) void scan1_kernel(const int* __restrict__ cnt,
                                                    int* __restrict__ rp,
                                                    int* __restrict__ bsums, int n) {
    __shared__ int sm[256];
    int b = blockIdx.x, tid = threadIdx.x;
    int base = b * 1024 + tid * 4;
    int v0 = 0, v1 = 0, v2 = 0, v3 = 0;
    if (base + 3 < n) {
        int4 q = *reinterpret_cast<const int4*>(&cnt[base]);
        v0 = q.x; v1 = q.y; v2 = q.z; v3 = q.w;
    } else {
        if (base + 0 < n) v0 = cnt[base + 0];
        if (base + 1 < n) v1 = cnt[base + 1];
        if (base + 2 < n) v2 = cnt[base + 2];
        if (base + 3 < n) v3 = cnt[base + 3];
    }
    int s1 = v0 + v1, s2 = s1 + v2, s3 = s2 + v3;
    sm[tid] = s3;
    __syncthreads();
    for (int off = 1; off < 256; off <<= 1) {
        int t = (tid >= off) ? sm[tid - off] : 0;
        __syncthreads();
        sm[tid] += t;
        __syncthreads();
    }
    int prefix = (tid > 0) ? sm[tid - 1] : 0;
    if (base + 0 < n) rp[base + 1] = prefix + v0;
    if (base + 1 < n) rp[base + 2] = prefix + s1;
    if (base + 2 < n) rp[base + 3] = prefix + s2;
    if (base + 3 < n) rp[base + 4] = prefix + s3;
    if (tid == 255) bsums[b] = sm[255];
    if (b == 0 && tid == 0) rp[0] = 0;
}

__global__ __launch_bounds__(256) void scan2_kernel(int* __restrict__ bsums, int nb) {
    __shared__ int sm[256];
    int tid = threadIdx.x;
    int v = (tid < nb) ? bsums[tid] : 0;
    sm[tid] = v;
    __syncthreads();
    for (int off = 1; off < 256; off <<= 1) {
        int t = (tid >= off) ? sm[tid - off] : 0;
        __syncthreads();
        sm[tid] += t;
        __syncthreads();
    }
    if (tid < nb) bsums[tid] = sm[tid] - v;  // exclusive
}

__global__ __launch_bounds__(256) void scan3_kernel(int* __restrict__ rp,
                                                    const int* __restrict__ bsums, int n) {
    int b = blockIdx.x, tid = threadIdx.x;
    if (b == 0) return;
    int add = bsums[b];
    int idx = b * 1024 + tid * 4;
#pragma unroll
    for (int u = 1; u <= 4; u++) {
        int p = idx + u;
        if (p <= n) rp[p] += add;
    }
}

__global__ void scatter_kernel(const int* __restrict__ dst, const int* __restrict__ src,
                               int* __restrict__ cursor, int* __restrict__ csrsrc, int E) {
    int i = blockIdx.x * blockDim.x + threadIdx.x;
    if (i < E) {
        int p = atomicAdd(&cursor[dst[i]], 1);
        csrsrc[p] = src[i];
    }
}

// ---------------- per-edge alpha: one wave per dst node (4 waves/block)
__global__ __launch_bounds__(256) void alpha_kernel(const float* __restrict__ el,
                                                    const float* __restrict__ er,
                                                    const int* __restrict__ rp,
                                                    const int* __restrict__ csrsrc,
                                                    float* __restrict__ alpha, int n_dst) {
    int wid = (blockIdx.x * 256 + threadIdx.x) >> 6;
    int lane = threadIdx.x & 63;
    if (wid >= n_dst) return;
    int begin = rp[wid], end = rp[wid + 1];
    float4 erv = *reinterpret_cast<const float4*>(&er[wid * 4]);
    float m[4], s[4];
#pragma unroll
    for (int h = 0; h < 4; h++) { m[h] = -1e30f; s[h] = 0.f; }
    for (int i = begin + lane; i < end; i += 64) {
        int sn = csrsrc[i];
        float4 elv = *reinterpret_cast<const float4*>(&el[sn * 4]);
        float v[4] = {elv.x + erv.x, elv.y + erv.y, elv.z + erv.z, elv.w + erv.w};
#pragma unroll
        for (int h = 0; h < 4; h++) {
            float vv = v[h] > 0.f ? v[h] : 0.2f * v[h];
            float nm = fmaxf(m[h], vv);
            s[h] = s[h] * __expf(m[h] - nm) + __expf(vv - nm);
            m[h] = nm;
        }
    }
#pragma unroll
    for (int off = 1; off < 64; off <<= 1) {
#pragma unroll
        for (int h = 0; h < 4; h++) {
            float om = __shfl_xor(m[h], off);
            float os = __shfl_xor(s[h], off);
            float nm = fmaxf(m[h], om);
            s[h] = s[h] * __expf(m[h] - nm) + os * __expf(om - nm);
            m[h] = nm;
        }
    }
    float inv[4];
#pragma unroll
    for (int h = 0; h < 4; h++) inv[h] = s[h] > 0.f ? 1.f / s[h] : 0.f;
    for (int i = begin + lane; i < end; i += 64) {
        int sn = csrsrc[i];
        float4 elv = *reinterpret_cast<const float4*>(&el[sn * 4]);
        float v[4] = {elv.x + erv.x, elv.y + erv.y, elv.z + erv.z, elv.w + erv.w};
        float a[4];
#pragma unroll
        for (int h = 0; h < 4; h++) {
            float vv = v[h] > 0.f ? v[h] : 0.2f * v[h];
            a[h] = __expf(vv - m[h]) * inv[h];
        }
        *reinterpret_cast<float4*>(&alpha[(size_t)i * 4]) = make_float4(a[0], a[1], a[2], a[3]);
    }
}

// ---------------- layer-1 aggregation: block per dst, 4 waves x 4-edges-in-flight, float4
#define CHUNK 128
__global__ __launch_bounds__(256) void agg1_kernel(const float* __restrict__ feat,
                                                   const float* __restrict__ alpha,
                                                   const int* __restrict__ rp,
                                                   const int* __restrict__ csrsrc,
                                                   const float* __restrict__ bias,
                                                   float* __restrict__ h1) {
    int dstn = blockIdx.x;
    int tid = threadIdx.x;
    int wave = tid >> 6, lane = tid & 63;
    __shared__ int s_src[CHUNK];
    __shared__ __align__(16) float s_alpha[CHUNK][4];
    __shared__ __align__(16) float s_red[3][256];
    int begin = rp[dstn], end = rp[dstn + 1];
    int head = lane >> 4;
    float4 acc = make_float4(0.f, 0.f, 0.f, 0.f);

    for (int cbase = begin; cbase < end; cbase += CHUNK) {
        int cn = min(end - cbase, CHUNK);
        for (int j = tid; j < cn; j += 256) {
            s_src[j] = csrsrc[cbase + j];
            *reinterpret_cast<float4*>(&s_alpha[j][0]) =
                *reinterpret_cast<const float4*>(&alpha[(size_t)(cbase + j) * 4]);
        }
        __syncthreads();
        for (int j = wave; j < cn; j += 4) {
            int sn = s_src[j];
            float a = s_alpha[j][head];
            float4 f = *reinterpret_cast<const float4*>(&feat[(size_t)sn * CHD1 + lane * 4]);
            acc.x += a * f.x; acc.y += a * f.y; acc.z += a * f.z; acc.w += a * f.w;
        }
        __syncthreads();
    }
    if (wave > 0) *reinterpret_cast<float4*>(&s_red[wave - 1][lane * 4]) = acc;
    __syncthreads();
    if (wave == 0) {
#pragma unroll
        for (int w = 0; w < 3; w++) {
            float4 o = *reinterpret_cast<float4*>(&s_red[w][lane * 4]);
            acc.x += o.x; acc.y += o.y; acc.z += o.z; acc.w += o.w;
        }
        float4 b = *reinterpret_cast<const float4*>(&bias[lane * 4]);
        float r[4] = {acc.x + b.x, acc.y + b.y, acc.z + b.z, acc.w + b.w};
#pragma unroll
        for (int u = 0; u < 4; u++) r[u] = r[u] > 0.f ? r[u] : expm1f(r[u]);  // ELU
        *reinterpret_cast<float4*>(&h1[(size_t)dstn * CHD1 + lane * 4]) =
            make_float4(r[0], r[1], r[2], r[3]);
    }
}

// ---------------- layer-2 aggregation: block per dst, 188 feats strided, fused head-mean
__global__ __launch_bounds__(256) void agg2_kernel(const float* __restrict__ feat,
                                                   const float* __restrict__ alpha,
                                                   const int* __restrict__ rp,
                                                   const int* __restrict__ csrsrc,
                                                   const float* __restrict__ bias,
                                                   float* __restrict__ out) {
    int dstn = blockIdx.x;
    int tid = threadIdx.x;
    int wave = tid >> 6, lane = tid & 63;
    __shared__ int s_src[CHUNK];
    __shared__ __align__(16) float s_alpha[CHUNK][4];
    __shared__ float s_red[3][192];
    __shared__ float s_out[192];
    int begin = rp[dstn], end = rp[dstn + 1];
    int f0 = lane, f1 = lane + 64, f2 = lane + 128;
    int h0 = f0 / CNC, h1_ = f1 / CNC, h2 = f2 < CHC2 ? f2 / CNC : 3;
    float a0c = 0.f, a1c = 0.f, a2c = 0.f;

    for (int cbase = begin; cbase < end; cbase += CHUNK) {
        int cn = min(end - cbase, CHUNK);
        for (int j = tid; j < cn; j += 256) {
            s_src[j] = csrsrc[cbase + j];
            *reinterpret_cast<float4*>(&s_alpha[j][0]) =
                *reinterpret_cast<const float4*>(&alpha[(size_t)(cbase + j) * 4]);
        }
        __syncthreads();
        for (int j = wave; j < cn; j += 4) {
            int sn = s_src[j];
            const float* fr = &feat[(size_t)sn * CHC2];
            a0c += s_alpha[j][h0] * fr[f0];
            a1c += s_alpha[j][h1_] * fr[f1];
            if (f2 < CHC2) a2c += s_alpha[j][h2] * fr[f2];
        }
        __syncthreads();
    }
    if (wave > 0) {
        s_red[wave - 1][f0] = a0c;
        s_red[wave - 1][f1] = a1c;
        if (f2 < 192) s_red[wave - 1][f2] = a2c;
    }
    __syncthreads();
    if (wave == 0) {
#pragma unroll
        for (int w = 0; w < 3; w++) {
            a0c += s_red[w][f0];
            a1c += s_red[w][f1];
            if (f2 < 192) a2c += s_red[w][f2];
        }
        s_out[f0] = a0c + bias[f0];
        if (f1 < CHC2) s_out[f1] = a1c + bias[f1];
        if (f2 < CHC2) s_out[f2] = a2c + bias[f2];
    }
    __syncthreads();
    if (tid < CNC) {
        out[(size_t)dstn * CNC + tid] =
            0.25f * (s_out[tid] + s_out[CNC + tid] + s_out[2 * CNC + tid] + s_out[3 * CNC + tid]);
    }
}

extern "C" void kernel_launch(void* const* d_in, const int* in_sizes, int n_in,
                              void* d_out, int out_size, void* d_ws, size_t ws_size,
                              hipStream_t stream) {
    const float* x   = (const float*)d_in[0];
    const float* W1  = (const float*)d_in[1];
    const float* al1 = (const float*)d_in[2];
    const float* ar1 = (const float*)d_in[3];
    const float* b1  = (const float*)d_in[4];
    const float* W2  = (const float*)d_in[5];
    const float* al2 = (const float*)d_in[6];
    const float* ar2 = (const float*)d_in[7];
    const float* b2  = (const float*)d_in[8];
    const int* src0  = (const int*)d_in[9];
    const int* dst0  = (const int*)d_in[10];
    const int* src1  = (const int*)d_in[11];
    const int* dst1  = (const int*)d_in[12];
    float* out = (float*)d_out;

    char* base = (char*)d_ws;
    size_t off = 0;
    auto carve = [&](size_t bytes) {
        void* p = base + off;
        off = (off + bytes + 255) & ~(size_t)255;
        return p;
    };
    float* feat1   = (float*)carve((size_t)CN0 * CHD1 * 4);  // 102.4 MB; feat2 aliases
    float* h1      = (float*)carve((size_t)CN1 * CHD1 * 4);  // 51.2 MB
    float* el1     = (float*)carve((size_t)CN0 * CNH * 4);
    float* er1     = (float*)carve((size_t)CN1 * CNH * 4);
    int* rp0       = (int*)carve((CN1 + 1) * 4);
    int* cnt0      = (int*)carve(CN1 * 4);
    int* csrsrc0   = (int*)carve((size_t)CE0 * 4);
    float* alpha0  = (float*)carve((size_t)CE0 * CNH * 4);   // 9.6 MB
    int* rp1       = (int*)carve((CN2 + 1) * 4);
    int* cnt1      = (int*)carve(CN2 * 4);
    int* csrsrc1   = (int*)carve((size_t)CE1 * 4);
    float* alpha1  = (float*)carve((size_t)CE1 * CNH * 4);
    int* bsums0    = (int*)carve(64 * 4);
    int* bsums1    = (int*)carve(64 * 4);
    __bf16* W1Th   = (__bf16*)carve((size_t)CHD1 * CFIN * 2);  // [256][256]
    __bf16* W1Tl   = (__bf16*)carve((size_t)CHD1 * CFIN * 2);
    __bf16* W2Th   = (__bf16*)carve((size_t)CHC2 * CHD1 * 2);  // [188][256]
    __bf16* W2Tl   = (__bf16*)carve((size_t)CHC2 * CHD1 * 2);
    float* feat2 = feat1;  // feat1 dead after agg1
    float* el2 = el1;
    float* er2 = er1;

    // ---- weight prep (split + transpose)
    prep_w_kernel<<<cdiv(CHD1 * CFIN, 256), 256, 0, stream>>>(W1, W1Th, W1Tl, CHD1);
    prep_w_kernel<<<cdiv(CHC2 * CHD1, 256), 256, 0, stream>>>(W2, W2Th, W2Tl, CHC2);

    // ---- CSR builds
    hipMemsetAsync(cnt0, 0, CN1 * 4, stream);
    hipMemsetAsync(cnt1, 0, CN2 * 4, stream);
    hist_kernel<<<cdiv(CE0, 256), 256, 0, stream>>>(dst0, cnt0, CE0);
    hist_kernel<<<cdiv(CE1, 256), 256, 0, stream>>>(dst1, cnt1, CE1);
    int nb0 = cdiv(CN1, 1024), nb1 = cdiv(CN2, 1024);
    scan1_kernel<<<nb0, 256, 0, stream>>>(cnt0, rp0, bsums0, CN1);
    scan1_kernel<<<nb1, 256, 0, stream>>>(cnt1, rp1, bsums1, CN2);
    scan2_kernel<<<1, 256, 0, stream>>>(bsums0, nb0);
    scan2_kernel<<<1, 256, 0, stream>>>(bsums1, nb1);
    scan3_kernel<<<nb0, 256, 0, stream>>>(rp0, bsums0, CN1);
    scan3_kernel<<<nb1, 256, 0, stream>>>(rp1, bsums1, CN2);
    hipMemcpyAsync(cnt0, rp0, CN1 * 4, hipMemcpyDeviceToDevice, stream);
    hipMemcpyAsync(cnt1, rp1, CN2 * 4, hipMemcpyDeviceToDevice, stream);
    scatter_kernel<<<cdiv(CE0, 256), 256, 0, stream>>>(dst0, src0, cnt0, csrsrc0, CE0);
    scatter_kernel<<<cdiv(CE1, 256), 256, 0, stream>>>(dst1, src1, cnt1, csrsrc1, CE1);

    // ---- layer 1
    gemm_mfma_kernel<<<dim3(cdiv(CN0, 128), cdiv(CHD1, 128)), 256, 0, stream>>>(
        x, W1Th, W1Tl, feat1, CN0, CHD1, CFIN);
    scores1_kernel<<<CN0, 256, 0, stream>>>(feat1, al1, ar1, el1, er1, CN1);
    alpha_kernel<<<cdiv(CN1, 4), 256, 0, stream>>>(el1, er1, rp0, csrsrc0, alpha0, CN1);
    agg1_kernel<<<CN1, 256, 0, stream>>>(feat1, alpha0, rp0, csrsrc0, b1, h1);

    // ---- layer 2
    gemm_mfma_kernel<<<dim3(cdiv(CN1, 128), cdiv(CHC2, 128)), 256, 0, stream>>>(
        h1, W2Th, W2Tl, feat2, CN1, CHC2, CHD1);
    scores2_kernel<<<CN1, 192, 0, stream>>>(feat2, al2, ar2, el2, er2, CN2);
    alpha_kernel<<<cdiv(CN2, 4), 256, 0, stream>>>(el2, er2, rp1, csrsrc1, alpha1, CN2);
    agg2_kernel<<<CN2, 256, 0, stream>>>(feat2, alpha1, rp1, csrsrc1, b2, out);
}

// Round 5
// 552.141 us; speedup vs baseline: 1.6768x; 1.0348x over previous
//
#include <hip/hip_runtime.h>

#define CN0 100000
#define CN1 50000
#define CN2 8000
#define CE0 600000
#define CE1 80000
#define CFIN 256
#define CHID 64
#define CNH 4
#define CNC 47
#define CHD1 256   // NH*HID
#define CHC2 188   // NH*NC

static __host__ __device__ inline int cdiv(int a, int b) { return (a + b - 1) / b; }

typedef __bf16 bf16x8 __attribute__((ext_vector_type(8)));
typedef __bf16 bf16x4 __attribute__((ext_vector_type(4)));
typedef float f32x16 __attribute__((ext_vector_type(16)));

// ---------------- W prep (both layers in one launch):
// W[K][N] f32 -> WT_hi[N][K], WT_lo[N][K] bf16 (transposed, split). K=256 for both.
__global__ __launch_bounds__(256) void prep_w2_kernel(const float* __restrict__ W1,
                                                      __bf16* __restrict__ W1Th,
                                                      __bf16* __restrict__ W1Tl,
                                                      const float* __restrict__ W2,
                                                      __bf16* __restrict__ W2Th,
                                                      __bf16* __restrict__ W2Tl) {
    int id = blockIdx.x * 256 + threadIdx.x;
    const int tot1 = CHD1 * CFIN;
    if (id < tot1) {
        int n = id >> 8, k = id & 255;
        float w = W1[(size_t)k * CHD1 + n];
        __bf16 h = (__bf16)w;
        W1Th[id] = h;
        W1Tl[id] = (__bf16)(w - (float)h);
    } else {
        int id2 = id - tot1;
        if (id2 >= CHC2 * CHD1) return;
        int n = id2 >> 8, k = id2 & 255;
        float w = W2[(size_t)k * CHC2 + n];
        __bf16 h = (__bf16)w;
        W2Th[id2] = h;
        W2Tl[id2] = (__bf16)(w - (float)h);
    }
}

// ---------------- split-bf16 MFMA GEMM with register-prefetch double buffering.
// C[M,N] = A[M,K] @ B[K,N]; ASPLIT: A is f32 (split in-kernel); else A pre-split bf16.
// B pre-split as BT_hi/BT_lo [N][K] bf16. Block 128x128, BK=32, 4 waves, 2x2 frags 32x32x16.
#define KP 40  // padded LDS k-stride (bf16): 80B rows -> max 4-way bank conflicts
template <bool ASPLIT>
__global__ __launch_bounds__(256) void gemm_mfma_kernel(const float* __restrict__ Af,
                                                        const __bf16* __restrict__ Ahp,
                                                        const __bf16* __restrict__ Alp,
                                                        const __bf16* __restrict__ BTh,
                                                        const __bf16* __restrict__ BTl,
                                                        float* __restrict__ C,
                                                        int M, int N, int K) {
    __shared__ __align__(16) __bf16 Ah[128 * KP];
    __shared__ __align__(16) __bf16 Al[128 * KP];
    __shared__ __align__(16) __bf16 Bh[128 * KP];
    __shared__ __align__(16) __bf16 Bl[128 * KP];
    int tid = threadIdx.x;
    int wave = tid >> 6, lane = tid & 63;
    int rowBase = blockIdx.x * 128, colBase = blockIdx.y * 128;
    int wr = wave >> 1, wc = wave & 1;

    f32x16 acc[2][2];
#pragma unroll
    for (int m = 0; m < 2; m++)
#pragma unroll
        for (int n = 0; n < 2; n++)
#pragma unroll
            for (int r = 0; r < 16; r++) acc[m][n][r] = 0.f;

    // staging roles
    const int arow = tid >> 1;          // 0..127
    const int akc = (tid & 1) * 16;     // 0 or 16
    const int bcol = tid & 127;         // 0..127
    const int bsel = tid >> 7;          // 0 -> hi, 1 -> lo
    const bool avalid = (rowBase + arow) < M;
    const int gcol = colBase + bcol;
    const bool bvalid = gcol < N;
    const float* aF = &Af[(size_t)(rowBase + arow) * K + akc];
    const __bf16* aH = &Ahp[(size_t)(rowBase + arow) * K + akc];
    const __bf16* aL = &Alp[(size_t)(rowBase + arow) * K + akc];
    const __bf16* bptr = (bsel ? BTl : BTh) + (size_t)gcol * K;
    __bf16* bdst = (bsel ? Bl : Bh) + bcol * KP;

    const int rc = lane & 31;
    const int kb = (lane >> 5) * 8;     // 0 or 8

    // prefetch registers
    float4 pa[4];
    bf16x8 pah[2], pal[2];
    bf16x8 pb[4];

    auto LOAD = [&](int k0) {
        if constexpr (ASPLIT) {
#pragma unroll
            for (int c = 0; c < 4; c++)
                pa[c] = avalid ? *reinterpret_cast<const float4*>(aF + k0 + c * 4)
                               : make_float4(0.f, 0.f, 0.f, 0.f);
        } else {
            bf16x8 z = {};
            pah[0] = avalid ? *reinterpret_cast<const bf16x8*>(aH + k0) : z;
            pah[1] = avalid ? *reinterpret_cast<const bf16x8*>(aH + k0 + 8) : z;
            pal[0] = avalid ? *reinterpret_cast<const bf16x8*>(aL + k0) : z;
            pal[1] = avalid ? *reinterpret_cast<const bf16x8*>(aL + k0 + 8) : z;
        }
        bf16x8 z = {};
#pragma unroll
        for (int c = 0; c < 4; c++)
            pb[c] = bvalid ? *reinterpret_cast<const bf16x8*>(&bptr[k0 + c * 8]) : z;
    };

    auto STORE = [&]() {
        if constexpr (ASPLIT) {
#pragma unroll
            for (int c = 0; c < 4; c++) {
                float4 v = pa[c];
                __bf16 h0 = (__bf16)v.x, h1 = (__bf16)v.y, h2 = (__bf16)v.z, h3 = (__bf16)v.w;
                bf16x4 hv = {h0, h1, h2, h3};
                bf16x4 lv = {(__bf16)(v.x - (float)h0), (__bf16)(v.y - (float)h1),
                             (__bf16)(v.z - (float)h2), (__bf16)(v.w - (float)h3)};
                int o = arow * KP + akc + c * 4;
                *reinterpret_cast<bf16x4*>(&Ah[o]) = hv;
                *reinterpret_cast<bf16x4*>(&Al[o]) = lv;
            }
        } else {
            int o = arow * KP + akc;
            *reinterpret_cast<bf16x8*>(&Ah[o]) = pah[0];
            *reinterpret_cast<bf16x8*>(&Ah[o + 8]) = pah[1];
            *reinterpret_cast<bf16x8*>(&Al[o]) = pal[0];
            *reinterpret_cast<bf16x8*>(&Al[o + 8]) = pal[1];
        }
#pragma unroll
        for (int c = 0; c < 4; c++) *reinterpret_cast<bf16x8*>(&bdst[c * 8]) = pb[c];
    };

    const int nK = K >> 5;
    LOAD(0);
    for (int t = 0; t < nK; t++) {
        __syncthreads();          // previous tile's consumers done
        STORE();                  // regs -> LDS (waits on the loads)
        __syncthreads();
        if (t + 1 < nK) LOAD((t + 1) * 32);  // issue next tile early; latency hides under MFMA

#pragma unroll
        for (int ks = 0; ks < 32; ks += 16) {
            bf16x8 fah[2], fal[2], fbh[2], fbl[2];
#pragma unroll
            for (int m = 0; m < 2; m++) {
                int r = wr * 64 + m * 32 + rc;
                fah[m] = *reinterpret_cast<const bf16x8*>(&Ah[r * KP + ks + kb]);
                fal[m] = *reinterpret_cast<const bf16x8*>(&Al[r * KP + ks + kb]);
            }
#pragma unroll
            for (int n = 0; n < 2; n++) {
                int cL = wc * 64 + n * 32 + rc;
                fbh[n] = *reinterpret_cast<const bf16x8*>(&Bh[cL * KP + ks + kb]);
                fbl[n] = *reinterpret_cast<const bf16x8*>(&Bl[cL * KP + ks + kb]);
            }
#pragma unroll
            for (int m = 0; m < 2; m++)
#pragma unroll
                for (int n = 0; n < 2; n++) {
                    acc[m][n] = __builtin_amdgcn_mfma_f32_32x32x16_bf16(fah[m], fbh[n],
                                                                        acc[m][n], 0, 0, 0);
                    acc[m][n] = __builtin_amdgcn_mfma_f32_32x32x16_bf16(fah[m], fbl[n],
                                                                        acc[m][n], 0, 0, 0);
                    acc[m][n] = __builtin_amdgcn_mfma_f32_32x32x16_bf16(fal[m], fbh[n],
                                                                        acc[m][n], 0, 0, 0);
                }
        }
    }

    // ---- epilogue: D layout col=lane&31, row=(r&3)+8*(r>>2)+4*(lane>>5)
#pragma unroll
    for (int m = 0; m < 2; m++)
#pragma unroll
        for (int n = 0; n < 2; n++) {
            int col = colBase + wc * 64 + n * 32 + rc;
            if (col >= N) continue;
            int rbase = rowBase + wr * 64 + m * 32 + 4 * (lane >> 5);
#pragma unroll
            for (int r = 0; r < 16; r++) {
                int row = rbase + (r & 3) + 8 * (r >> 2);
                if (row < M) C[(size_t)row * N + col] = acc[m][n][r];
            }
        }
}

// ---------------- scores layer1
__global__ __launch_bounds__(256) void scores1_kernel(const float* __restrict__ feat,
                                                      const float* __restrict__ al,
                                                      const float* __restrict__ ar,
                                                      float* __restrict__ el,
                                                      float* __restrict__ er, int n_dst) {
    int n = blockIdx.x;
    int tid = threadIdx.x;
    int h = tid >> 6, dd = tid & 63;
    float f = feat[(size_t)n * CHD1 + tid];
    float pl = f * al[h * CHID + dd];
    float pr = f * ar[h * CHID + dd];
#pragma unroll
    for (int off = 32; off > 0; off >>= 1) {
        pl += __shfl_down(pl, off);
        pr += __shfl_down(pr, off);
    }
    if (dd == 0) {
        el[n * CNH + h] = pl;
        if (n < n_dst) er[n * CNH + h] = pr;
    }
}

// ---------------- scores layer2
__global__ __launch_bounds__(192) void scores2_kernel(const float* __restrict__ feat,
                                                      const float* __restrict__ al,
                                                      const float* __restrict__ ar,
                                                      float* __restrict__ el,
                                                      float* __restrict__ er, int n_dst) {
    int n = blockIdx.x;
    int tid = threadIdx.x;
    __shared__ float pl[CHC2], pr[CHC2];
    if (tid < CHC2) {
        float f = feat[(size_t)n * CHC2 + tid];
        pl[tid] = f * al[tid];
        pr[tid] = f * ar[tid];
    }
    __syncthreads();
    if (tid < CNH) {
        float sl = 0.f, sr = 0.f;
        for (int c = 0; c < CNC; c++) {
            sl += pl[tid * CNC + c];
            sr += pr[tid * CNC + c];
        }
        el[n * CNH + tid] = sl;
        if (n < n_dst) er[n * CNH + tid] = sr;
    }
}

// ---------------- CSR build (both graphs per launch)
__global__ void hist2_kernel(const int* __restrict__ dst0, int* __restrict__ cnt0,
                             const int* __restrict__ dst1, int* __restrict__ cnt1) {
    int i = blockIdx.x * blockDim.x + threadIdx.x;
    if (i < CE0) {
        atomicAdd(&cnt0[dst0[i]], 1);
    } else {
        int j = i - CE0;
        if (j < CE1) atomicAdd(&cnt1[dst1[j]], 1);
    }
}

// per-1024-chunk scan; writes rp[i+1] (inclusive) and cur[i] (exclusive cursor)
__global__ __launch_bounds__(256) void scan1_kernel(const int* __restrict__ cnt0,
                                                    int* __restrict__ rp0, int* __restrict__ cur0,
                                                    int* __restrict__ bsums0, int nb0,
                                                    const int* __restrict__ cnt1,
                                                    int* __restrict__ rp1, int* __restrict__ cur1,
                                                    int* __restrict__ bsums1) {
    __shared__ int sm[256];
    int gb = blockIdx.x, tid = threadIdx.x;
    const int* cnt; int* rp; int* cur; int* bsums; int n; int b;
    if (gb < nb0) { cnt = cnt0; rp = rp0; cur = cur0; bsums = bsums0; n = CN1; b = gb; }
    else          { cnt = cnt1; rp = rp1; cur = cur1; bsums = bsums1; n = CN2; b = gb - nb0; }
    int base = b * 1024 + tid * 4;
    int v0 = 0, v1 = 0, v2 = 0, v3 = 0;
    if (base + 3 < n) {
        int4 q = *reinterpret_cast<const int4*>(&cnt[base]);
        v0 = q.x; v1 = q.y; v2 = q.z; v3 = q.w;
    } else {
        if (base + 0 < n) v0 = cnt[base + 0];
        if (base + 1 < n) v1 = cnt[base + 1];
        if (base + 2 < n) v2 = cnt[base + 2];
        if (base + 3 < n) v3 = cnt[base + 3];
    }
    int s1 = v0 + v1, s2 = s1 + v2, s3 = s2 + v3;
    sm[tid] = s3;
    __syncthreads();
    for (int off = 1; off < 256; off <<= 1) {
        int t = (tid >= off) ? sm[tid - off] : 0;
        __syncthreads();
        sm[tid] += t;
        __syncthreads();
    }
    int prefix = (tid > 0) ? sm[tid - 1] : 0;
    if (base + 0 < n) { rp[base + 1] = prefix + v0; cur[base + 0] = prefix; }
    if (base + 1 < n) { rp[base + 2] = prefix + s1; cur[base + 1] = prefix + v0; }
    if (base + 2 < n) { rp[base + 3] = prefix + s2; cur[base + 2] = prefix + s1; }
    if (base + 3 < n) { rp[base + 4] = prefix + s3; cur[base + 3] = prefix + s2; }
    if (tid == 255) bsums[b] = sm[255];
    if (b == 0 && tid == 0) rp[0] = 0;
}

__global__ __launch_bounds__(256) void scan2_kernel(int* __restrict__ bsums0, int nb0,
                                                    int* __restrict__ bsums1, int nb1) {
    __shared__ int sm[256];
    int tid = threadIdx.x;
    int* bsums = (blockIdx.x == 0) ? bsums0 : bsums1;
    int nb = (blockIdx.x == 0) ? nb0 : nb1;
    int v = (tid < nb) ? bsums[tid] : 0;
    sm[tid] = v;
    __syncthreads();
    for (int off = 1; off < 256; off <<= 1) {
        int t = (tid >= off) ? sm[tid - off] : 0;
        __syncthreads();
        sm[tid] += t;
        __syncthreads();
    }
    if (tid < nb) bsums[tid] = sm[tid] - v;  // exclusive
}

__global__ __launch_bounds__(256) void scan3_kernel(int* __restrict__ rp0, int* __restrict__ cur0,
                                                    const int* __restrict__ bsums0, int nb0,
                                                    int* __restrict__ rp1, int* __restrict__ cur1,
                                                    const int* __restrict__ bsums1) {
    int gb = blockIdx.x, tid = threadIdx.x;
    int* rp; int* cur; const int* bsums; int n; int b;
    if (gb < nb0) { rp = rp0; cur = cur0; bsums = bsums0; n = CN1; b = gb; }
    else          { rp = rp1; cur = cur1; bsums = bsums1; n = CN2; b = gb - nb0; }
    if (b == 0) return;
    int add = bsums[b];
    int idx = b * 1024 + tid * 4;
#pragma unroll
    for (int u = 0; u < 4; u++) {
        int p = idx + u;
        if (p < n) cur[p] += add;
        if (p + 1 <= n) rp[p + 1] += add;
    }
}

__global__ void scatter2_kernel(const int* __restrict__ dst0, const int* __restrict__ src0,
                                int* __restrict__ cur0, int* __restrict__ csr0,
                                const int* __restrict__ dst1, const int* __restrict__ src1,
                                int* __restrict__ cur1, int* __restrict__ csr1) {
    int i = blockIdx.x * blockDim.x + threadIdx.x;
    if (i < CE0) {
        int p = atomicAdd(&cur0[dst0[i]], 1);
        csr0[p] = src0[i];
    } else {
        int j = i - CE0;
        if (j < CE1) {
            int p = atomicAdd(&cur1[dst1[j]], 1);
            csr1[p] = src1[j];
        }
    }
}

// ---------------- per-edge alpha: one wave per dst node
__global__ __launch_bounds__(256) void alpha_kernel(const float* __restrict__ el,
                                                    const float* __restrict__ er,
                                                    const int* __restrict__ rp,
                                                    const int* __restrict__ csrsrc,
                                                    float* __restrict__ alpha, int n_dst) {
    int wid = (blockIdx.x * 256 + threadIdx.x) >> 6;
    int lane = threadIdx.x & 63;
    if (wid >= n_dst) return;
    int begin = rp[wid], end = rp[wid + 1];
    float4 erv = *reinterpret_cast<const float4*>(&er[wid * 4]);
    float m[4], s[4];
#pragma unroll
    for (int h = 0; h < 4; h++) { m[h] = -1e30f; s[h] = 0.f; }
    for (int i = begin + lane; i < end; i += 64) {
        int sn = csrsrc[i];
        float4 elv = *reinterpret_cast<const float4*>(&el[sn * 4]);
        float v[4] = {elv.x + erv.x, elv.y + erv.y, elv.z + erv.z, elv.w + erv.w};
#pragma unroll
        for (int h = 0; h < 4; h++) {
            float vv = v[h] > 0.f ? v[h] : 0.2f * v[h];
            float nm = fmaxf(m[h], vv);
            s[h] = s[h] * __expf(m[h] - nm) + __expf(vv - nm);
            m[h] = nm;
        }
    }
#pragma unroll
    for (int off = 1; off < 64; off <<= 1) {
#pragma unroll
        for (int h = 0; h < 4; h++) {
            float om = __shfl_xor(m[h], off);
            float os = __shfl_xor(s[h], off);
            float nm = fmaxf(m[h], om);
            s[h] = s[h] * __expf(m[h] - nm) + os * __expf(om - nm);
            m[h] = nm;
        }
    }
    float inv[4];
#pragma unroll
    for (int h = 0; h < 4; h++) inv[h] = s[h] > 0.f ? 1.f / s[h] : 0.f;
    for (int i = begin + lane; i < end; i += 64) {
        int sn = csrsrc[i];
        float4 elv = *reinterpret_cast<const float4*>(&el[sn * 4]);
        float v[4] = {elv.x + erv.x, elv.y + erv.y, elv.z + erv.z, elv.w + erv.w};
        float a[4];
#pragma unroll
        for (int h = 0; h < 4; h++) {
            float vv = v[h] > 0.f ? v[h] : 0.2f * v[h];
            a[h] = __expf(vv - m[h]) * inv[h];
        }
        *reinterpret_cast<float4*>(&alpha[(size_t)i * 4]) = make_float4(a[0], a[1], a[2], a[3]);
    }
}

// ---------------- layer-1 aggregation; emits h1 as bf16 hi/lo (pre-split for GEMM2)
#define CHUNK 128
__global__ __launch_bounds__(256) void agg1_kernel(const float* __restrict__ feat,
                                                   const float* __restrict__ alpha,
                                                   const int* __restrict__ rp,
                                                   const int* __restrict__ csrsrc,
                                                   const float* __restrict__ bias,
                                                   __bf16* __restrict__ h1h,
                                                   __bf16* __restrict__ h1l) {
    int dstn = blockIdx.x;
    int tid = threadIdx.x;
    int wave = tid >> 6, lane = tid & 63;
    __shared__ int s_src[CHUNK];
    __shared__ __align__(16) float s_alpha[CHUNK][4];
    __shared__ __align__(16) float s_red[3][256];
    int begin = rp[dstn], end = rp[dstn + 1];
    int head = lane >> 4;
    float4 acc = make_float4(0.f, 0.f, 0.f, 0.f);

    for (int cbase = begin; cbase < end; cbase += CHUNK) {
        int cn = min(end - cbase, CHUNK);
        for (int j = tid; j < cn; j += 256) {
            s_src[j] = csrsrc[cbase + j];
            *reinterpret_cast<float4*>(&s_alpha[j][0]) =
                *reinterpret_cast<const float4*>(&alpha[(size_t)(cbase + j) * 4]);
        }
        __syncthreads();
        for (int j = wave; j < cn; j += 4) {
            int sn = s_src[j];
            float a = s_alpha[j][head];
            float4 f = *reinterpret_cast<const float4*>(&feat[(size_t)sn * CHD1 + lane * 4]);
            acc.x += a * f.x; acc.y += a * f.y; acc.z += a * f.z; acc.w += a * f.w;
        }
        __syncthreads();
    }
    if (wave > 0) *reinterpret_cast<float4*>(&s_red[wave - 1][lane * 4]) = acc;
    __syncthreads();
    if (wave == 0) {
#pragma unroll
        for (int w = 0; w < 3; w++) {
            float4 o = *reinterpret_cast<float4*>(&s_red[w][lane * 4]);
            acc.x += o.x; acc.y += o.y; acc.z += o.z; acc.w += o.w;
        }
        float4 b = *reinterpret_cast<const float4*>(&bias[lane * 4]);
        float r[4] = {acc.x + b.x, acc.y + b.y, acc.z + b.z, acc.w + b.w};
        bf16x4 hv, lv;
#pragma unroll
        for (int u = 0; u < 4; u++) {
            float e = r[u] > 0.f ? r[u] : expm1f(r[u]);  // ELU
            __bf16 h = (__bf16)e;
            hv[u] = h;
            lv[u] = (__bf16)(e - (float)h);
        }
        *reinterpret_cast<bf16x4*>(&h1h[(size_t)dstn * CHD1 + lane * 4]) = hv;
        *reinterpret_cast<bf16x4*>(&h1l[(size_t)dstn * CHD1 + lane * 4]) = lv;
    }
}

// ---------------- layer-2 aggregation (fused head-mean)
__global__ __launch_bounds__(256) void agg2_kernel(const float* __restrict__ feat,
                                                   const float* __restrict__ alpha,
                                                   const int* __restrict__ rp,
                                                   const int* __restrict__ csrsrc,
                                                   const float* __restrict__ bias,
                                                   float* __restrict__ out) {
    int dstn = blockIdx.x;
    int tid = threadIdx.x;
    int wave = tid >> 6, lane = tid & 63;
    __shared__ int s_src[CHUNK];
    __shared__ __align__(16) float s_alpha[CHUNK][4];
    __shared__ float s_red[3][192];
    __shared__ float s_out[192];
    int begin = rp[dstn], end = rp[dstn + 1];
    int f0 = lane, f1 = lane + 64, f2 = lane + 128;
    int h0 = f0 / CNC, h1_ = f1 / CNC, h2 = f2 < CHC2 ? f2 / CNC : 3;
    float a0c = 0.f, a1c = 0.f, a2c = 0.f;

    for (int cbase = begin; cbase < end; cbase += CHUNK) {
        int cn = min(end - cbase, CHUNK);
        for (int j = tid; j < cn; j += 256) {
            s_src[j] = csrsrc[cbase + j];
            *reinterpret_cast<float4*>(&s_alpha[j][0]) =
                *reinterpret_cast<const float4*>(&alpha[(size_t)(cbase + j) * 4]);
        }
        __syncthreads();
        for (int j = wave; j < cn; j += 4) {
            int sn = s_src[j];
            const float* fr = &feat[(size_t)sn * CHC2];
            a0c += s_alpha[j][h0] * fr[f0];
            a1c += s_alpha[j][h1_] * fr[f1];
            if (f2 < CHC2) a2c += s_alpha[j][h2] * fr[f2];
        }
        __syncthreads();
    }
    if (wave > 0) {
        s_red[wave - 1][f0] = a0c;
        s_red[wave - 1][f1] = a1c;
        if (f2 < 192) s_red[wave - 1][f2] = a2c;
    }
    __syncthreads();
    if (wave == 0) {
#pragma unroll
        for (int w = 0; w < 3; w++) {
            a0c += s_red[w][f0];
            a1c += s_red[w][f1];
            if (f2 < 192) a2c += s_red[w][f2];
        }
        s_out[f0] = a0c + bias[f0];
        if (f1 < CHC2) s_out[f1] = a1c + bias[f1];
        if (f2 < CHC2) s_out[f2] = a2c + bias[f2];
    }
    __syncthreads();
    if (tid < CNC) {
        out[(size_t)dstn * CNC + tid] =
            0.25f * (s_out[tid] + s_out[CNC + tid] + s_out[2 * CNC + tid] + s_out[3 * CNC + tid]);
    }
}

extern "C" void kernel_launch(void* const* d_in, const int* in_sizes, int n_in,
                              void* d_out, int out_size, void* d_ws, size_t ws_size,
                              hipStream_t stream) {
    const float* x   = (const float*)d_in[0];
    const float* W1  = (const float*)d_in[1];
    const float* al1 = (const float*)d_in[2];
    const float* ar1 = (const float*)d_in[3];
    const float* b1  = (const float*)d_in[4];
    const float* W2  = (const float*)d_in[5];
    const float* al2 = (const float*)d_in[6];
    const float* ar2 = (const float*)d_in[7];
    const float* b2  = (const float*)d_in[8];
    const int* src0  = (const int*)d_in[9];
    const int* dst0  = (const int*)d_in[10];
    const int* src1  = (const int*)d_in[11];
    const int* dst1  = (const int*)d_in[12];
    float* out = (float*)d_out;

    char* base = (char*)d_ws;
    size_t off = 0;
    auto carve = [&](size_t bytes) {
        void* p = base + off;
        off = (off + bytes + 255) & ~(size_t)255;
        return p;
    };
    float* feat1   = (float*)carve((size_t)CN0 * CHD1 * 4);   // 102.4 MB; feat2 aliases
    __bf16* h1h    = (__bf16*)carve((size_t)CN1 * CHD1 * 2);  // 25.6 MB
    __bf16* h1l    = (__bf16*)carve((size_t)CN1 * CHD1 * 2);
    float* el1     = (float*)carve((size_t)CN0 * CNH * 4);
    float* er1     = (float*)carve((size_t)CN1 * CNH * 4);
    int* rp0       = (int*)carve((CN1 + 1) * 4);
    int* cnt0      = (int*)carve(CN1 * 4);                    // cnt0+cnt1 adjacent: 1 memset
    int* cnt1      = (int*)carve(CN2 * 4);
    int* csrsrc0   = (int*)carve((size_t)CE0 * 4);
    float* alpha0  = (float*)carve((size_t)CE0 * CNH * 4);    // 9.6 MB
    int* rp1       = (int*)carve((CN2 + 1) * 4);
    int* csrsrc1   = (int*)carve((size_t)CE1 * 4);
    float* alpha1  = (float*)carve((size_t)CE1 * CNH * 4);
    int* bsums0    = (int*)carve(64 * 4);
    int* bsums1    = (int*)carve(64 * 4);
    __bf16* W1Th   = (__bf16*)carve((size_t)CHD1 * CFIN * 2);
    __bf16* W1Tl   = (__bf16*)carve((size_t)CHD1 * CFIN * 2);
    __bf16* W2Th   = (__bf16*)carve((size_t)CHC2 * CHD1 * 2);
    __bf16* W2Tl   = (__bf16*)carve((size_t)CHC2 * CHD1 * 2);
    float* feat2 = feat1;  // feat1 dead after agg1
    float* el2 = el1;
    float* er2 = er1;

    // ---- weight prep (both layers, 1 launch)
    prep_w2_kernel<<<cdiv(CHD1 * CFIN + CHC2 * CHD1, 256), 256, 0, stream>>>(
        W1, W1Th, W1Tl, W2, W2Th, W2Tl);

    // ---- CSR builds (both graphs per launch; 6 ops total)
    hipMemsetAsync(cnt0, 0, (size_t)(CN1 + CN2 + 64) * 4, stream);  // covers cnt0+cnt1 (+pad)
    hist2_kernel<<<cdiv(CE0 + CE1, 256), 256, 0, stream>>>(dst0, cnt0, dst1, cnt1);
    int nb0 = cdiv(CN1, 1024), nb1 = cdiv(CN2, 1024);
    // cursor arrays: reuse cnt0/cnt1 (scan overwrites them with exclusive prefix)
    scan1_kernel<<<nb0 + nb1, 256, 0, stream>>>(cnt0, rp0, cnt0, bsums0, nb0,
                                                cnt1, rp1, cnt1, bsums1);
    scan2_kernel<<<2, 256, 0, stream>>>(bsums0, nb0, bsums1, nb1);
    scan3_kernel<<<nb0 + nb1, 256, 0, stream>>>(rp0, cnt0, bsums0, nb0, rp1, cnt1, bsums1);
    scatter2_kernel<<<cdiv(CE0 + CE1, 256), 256, 0, stream>>>(dst0, src0, cnt0, csrsrc0,
                                                              dst1, src1, cnt1, csrsrc1);

    // ---- layer 1
    gemm_mfma_kernel<true><<<dim3(cdiv(CN0, 128), cdiv(CHD1, 128)), 256, 0, stream>>>(
        x, nullptr, nullptr, W1Th, W1Tl, feat1, CN0, CHD1, CFIN);
    scores1_kernel<<<CN0, 256, 0, stream>>>(feat1, al1, ar1, el1, er1, CN1);
    alpha_kernel<<<cdiv(CN1, 4), 256, 0, stream>>>(el1, er1, rp0, csrsrc0, alpha0, CN1);
    agg1_kernel<<<CN1, 256, 0, stream>>>(feat1, alpha0, rp0, csrsrc0, b1, h1h, h1l);

    // ---- layer 2 (A pre-split by agg1)
    gemm_mfma_kernel<false><<<dim3(cdiv(CN1, 128), cdiv(CHC2, 128)), 256, 0, stream>>>(
        nullptr, h1h, h1l, W2Th, W2Tl, feat2, CN1, CHC2, CHD1);
    scores2_kernel<<<CN1, 192, 0, stream>>>(feat2, al2, ar2, el2, er2, CN2);
    alpha_kernel<<<cdiv(CN2, 4), 256, 0, stream>>>(el2, er2, rp1, csrsrc1, alpha1, CN2);
    agg2_kernel<<<CN2, 256, 0, stream>>>(feat2, alpha1, rp1, csrsrc1, b2, out);
}

// Round 7
// 533.071 us; speedup vs baseline: 1.7368x; 1.0358x over previous
//
#include <hip/hip_runtime.h>

#define CN0 100000
#define CN1 50000
#define CN2 8000
#define CE0 600000
#define CE1 80000
#define CFIN 256
#define CHID 64
#define CNH 4
#define CNC 47
#define CHD1 256   // NH*HID
#define CHC2 188   // NH*NC

static __host__ __device__ inline int cdiv(int a, int b) { return (a + b - 1) / b; }

typedef __bf16 bf16x8 __attribute__((ext_vector_type(8)));
typedef __bf16 bf16x4 __attribute__((ext_vector_type(4)));
typedef float f32x16 __attribute__((ext_vector_type(16)));

// ---------------- W prep (both layers in one launch):
// W[K][N] f32 -> WT_hi[N][K], WT_lo[N][K] bf16 (transposed, split). K=256 for both.
__global__ __launch_bounds__(256) void prep_w2_kernel(const float* __restrict__ W1,
                                                      __bf16* __restrict__ W1Th,
                                                      __bf16* __restrict__ W1Tl,
                                                      const float* __restrict__ W2,
                                                      __bf16* __restrict__ W2Th,
                                                      __bf16* __restrict__ W2Tl) {
    int id = blockIdx.x * 256 + threadIdx.x;
    const int tot1 = CHD1 * CFIN;
    if (id < tot1) {
        int n = id >> 8, k = id & 255;
        float w = W1[(size_t)k * CHD1 + n];
        __bf16 h = (__bf16)w;
        W1Th[id] = h;
        W1Tl[id] = (__bf16)(w - (float)h);
    } else {
        int id2 = id - tot1;
        if (id2 >= CHC2 * CHD1) return;
        int n = id2 >> 8, k = id2 & 255;
        float w = W2[(size_t)k * CHC2 + n];
        __bf16 h = (__bf16)w;
        W2Th[id2] = h;
        W2Tl[id2] = (__bf16)(w - (float)h);
    }
}

// ---------------- split-bf16 MFMA GEMM, double-buffered LDS, ONE barrier per K-step.
// C[M,N] = A[M,K] @ B[K,N]; ASPLIT: A f32 split in-kernel; else A pre-split bf16.
// SCORES: fuse GAT score dots into epilogue (head = 64-col groups, aligned to waves).
// Block 128x128, BK=32, 4 waves, wave tile 64x64 = 2x2 frags of 32x32x16.
// Dynamic LDS: 2 bufs x 4 arrays x [128][KP] bf16 = 81920 B.
#define KP 40  // padded LDS k-stride (bf16): 80B rows, 16B-aligned, 4-way conflicts max
template <bool ASPLIT, bool SCORES>
__global__ __launch_bounds__(256) void gemm_mfma_kernel(const float* __restrict__ Af,
                                                        const __bf16* __restrict__ Ahp,
                                                        const __bf16* __restrict__ Alp,
                                                        const __bf16* __restrict__ BTh,
                                                        const __bf16* __restrict__ BTl,
                                                        float* __restrict__ C,
                                                        int M, int N, int K,
                                                        const float* __restrict__ al,
                                                        const float* __restrict__ ar,
                                                        float* __restrict__ el,
                                                        float* __restrict__ er, int n_dst) {
    extern __shared__ __align__(16) __bf16 smem[];  // [8][128*KP]
    const int SZE = 128 * KP;
    int tid = threadIdx.x;
    int wave = tid >> 6, lane = tid & 63;
    int rowBase = blockIdx.x * 128, colBase = blockIdx.y * 128;
    int wr = wave >> 1, wc = wave & 1;

    f32x16 acc[2][2];
#pragma unroll
    for (int m = 0; m < 2; m++)
#pragma unroll
        for (int n = 0; n < 2; n++)
#pragma unroll
            for (int r = 0; r < 16; r++) acc[m][n][r] = 0.f;

    // staging roles
    const int arow = tid >> 1;          // 0..127
    const int akc = (tid & 1) * 16;     // 0 or 16
    const int bcol = tid & 127;         // 0..127
    const int bsel = tid >> 7;          // 0 -> hi, 1 -> lo
    const bool avalid = (rowBase + arow) < M;
    const int gcol = colBase + bcol;
    const bool bvalid = gcol < N;
    const float* aF = &Af[(size_t)(rowBase + arow) * K + akc];
    const __bf16* aH = &Ahp[(size_t)(rowBase + arow) * K + akc];
    const __bf16* aL = &Alp[(size_t)(rowBase + arow) * K + akc];
    const __bf16* bptr = (bsel ? BTl : BTh) + (size_t)gcol * K;

    const int rc = lane & 31;
    const int kb = (lane >> 5) * 8;     // 0 or 8

    // prefetch registers
    float4 pa[4];
    bf16x8 pah[2], pal[2];
    bf16x8 pb[4];

    auto LOAD = [&](int k0) {
        if constexpr (ASPLIT) {
#pragma unroll
            for (int c = 0; c < 4; c++)
                pa[c] = avalid ? *reinterpret_cast<const float4*>(aF + k0 + c * 4)
                               : make_float4(0.f, 0.f, 0.f, 0.f);
        } else {
            bf16x8 z = {};
            pah[0] = avalid ? *reinterpret_cast<const bf16x8*>(aH + k0) : z;
            pah[1] = avalid ? *reinterpret_cast<const bf16x8*>(aH + k0 + 8) : z;
            pal[0] = avalid ? *reinterpret_cast<const bf16x8*>(aL + k0) : z;
            pal[1] = avalid ? *reinterpret_cast<const bf16x8*>(aL + k0 + 8) : z;
        }
        bf16x8 z = {};
#pragma unroll
        for (int c = 0; c < 4; c++)
            pb[c] = bvalid ? *reinterpret_cast<const bf16x8*>(&bptr[k0 + c * 8]) : z;
    };

    auto STORE = [&](int buf) {
        __bf16* Ah = smem + (0 + buf) * SZE;
        __bf16* Al = smem + (2 + buf) * SZE;
        __bf16* Bdst = smem + ((bsel ? 6 : 4) + buf) * SZE + bcol * KP;
        if constexpr (ASPLIT) {
#pragma unroll
            for (int c = 0; c < 4; c++) {
                float4 v = pa[c];
                __bf16 h0 = (__bf16)v.x, h1 = (__bf16)v.y, h2 = (__bf16)v.z, h3 = (__bf16)v.w;
                bf16x4 hv = {h0, h1, h2, h3};
                bf16x4 lv = {(__bf16)(v.x - (float)h0), (__bf16)(v.y - (float)h1),
                             (__bf16)(v.z - (float)h2), (__bf16)(v.w - (float)h3)};
                int o = arow * KP + akc + c * 4;
                *reinterpret_cast<bf16x4*>(&Ah[o]) = hv;
                *reinterpret_cast<bf16x4*>(&Al[o]) = lv;
            }
        } else {
            int o = arow * KP + akc;
            *reinterpret_cast<bf16x8*>(&Ah[o]) = pah[0];
            *reinterpret_cast<bf16x8*>(&Ah[o + 8]) = pah[1];
            *reinterpret_cast<bf16x8*>(&Al[o]) = pal[0];
            *reinterpret_cast<bf16x8*>(&Al[o + 8]) = pal[1];
        }
#pragma unroll
        for (int c = 0; c < 4; c++) *reinterpret_cast<bf16x8*>(&Bdst[c * 8]) = pb[c];
    };

    const int nK = K >> 5;
    // prologue: fill buffer 0
    LOAD(0);
    STORE(0);
    __syncthreads();
    int cur = 0;

    for (int t = 0; t < nK; t++) {
        if (t + 1 < nK) LOAD((t + 1) * 32);  // in flight during this tile's MFMAs

        const __bf16* Ah = smem + (0 + cur) * SZE;
        const __bf16* Al = smem + (2 + cur) * SZE;
        const __bf16* Bh = smem + (4 + cur) * SZE;
        const __bf16* Bl = smem + (6 + cur) * SZE;
#pragma unroll
        for (int ks = 0; ks < 32; ks += 16) {
            bf16x8 fah[2], fal[2], fbh[2], fbl[2];
#pragma unroll
            for (int m = 0; m < 2; m++) {
                int r = wr * 64 + m * 32 + rc;
                fah[m] = *reinterpret_cast<const bf16x8*>(&Ah[r * KP + ks + kb]);
                fal[m] = *reinterpret_cast<const bf16x8*>(&Al[r * KP + ks + kb]);
            }
#pragma unroll
            for (int n = 0; n < 2; n++) {
                int cL = wc * 64 + n * 32 + rc;
                fbh[n] = *reinterpret_cast<const bf16x8*>(&Bh[cL * KP + ks + kb]);
                fbl[n] = *reinterpret_cast<const bf16x8*>(&Bl[cL * KP + ks + kb]);
            }
#pragma unroll
            for (int m = 0; m < 2; m++)
#pragma unroll
                for (int n = 0; n < 2; n++) {
                    acc[m][n] = __builtin_amdgcn_mfma_f32_32x32x16_bf16(fah[m], fbh[n],
                                                                        acc[m][n], 0, 0, 0);
                    acc[m][n] = __builtin_amdgcn_mfma_f32_32x32x16_bf16(fah[m], fbl[n],
                                                                        acc[m][n], 0, 0, 0);
                    acc[m][n] = __builtin_amdgcn_mfma_f32_32x32x16_bf16(fal[m], fbh[n],
                                                                        acc[m][n], 0, 0, 0);
                }
        }
        if (t + 1 < nK) STORE(cur ^ 1);  // vmcnt wait hidden behind the MFMA cluster
        __syncthreads();                 // single barrier per K-step
        cur ^= 1;
    }

    // ---- fused GAT scores (layer-1): head = 64-col group, aligned to (wc, n)
    if constexpr (SCORES) {
        int head = (colBase >> 6) + wc;
        float wa0 = al[head * 64 + rc], wa1 = al[head * 64 + 32 + rc];
        float wr0 = ar[head * 64 + rc], wr1 = ar[head * 64 + 32 + rc];
        int hi = lane >> 5;
#pragma unroll
        for (int m = 0; m < 2; m++) {
#pragma unroll
            for (int r = 0; r < 16; r++) {
                float vl = acc[m][0][r] * wa0 + acc[m][1][r] * wa1;
                float vr = acc[m][0][r] * wr0 + acc[m][1][r] * wr1;
#pragma unroll
                for (int off = 16; off > 0; off >>= 1) {
                    vl += __shfl_xor(vl, off);
                    vr += __shfl_xor(vr, off);
                }
                if (rc == 0) {
                    int row = rowBase + wr * 64 + m * 32 + 4 * hi + (r & 3) + 8 * (r >> 2);
                    if (row < M) {
                        el[row * CNH + head] = vl;
                        if (row < n_dst) er[row * CNH + head] = vr;
                    }
                }
            }
        }
    }

    // ---- epilogue: D layout col=lane&31, row=(r&3)+8*(r>>2)+4*(lane>>5)
#pragma unroll
    for (int m = 0; m < 2; m++)
#pragma unroll
        for (int n = 0; n < 2; n++) {
            int col = colBase + wc * 64 + n * 32 + rc;
            if (col >= N) continue;
            int rbase = rowBase + wr * 64 + m * 32 + 4 * (lane >> 5);
#pragma unroll
            for (int r = 0; r < 16; r++) {
                int row = rbase + (r & 3) + 8 * (r >> 2);
                if (row < M) C[(size_t)row * N + col] = acc[m][n][r];
            }
        }
}

// ---------------- scores layer2 (188-wide rows, heads of 47)
__global__ __launch_bounds__(192) void scores2_kernel(const float* __restrict__ feat,
                                                      const float* __restrict__ al,
                                                      const float* __restrict__ ar,
                                                      float* __restrict__ el,
                                                      float* __restrict__ er, int n_dst) {
    int n = blockIdx.x;
    int tid = threadIdx.x;
    __shared__ float pl[CHC2], pr[CHC2];
    if (tid < CHC2) {
        float f = feat[(size_t)n * CHC2 + tid];
        pl[tid] = f * al[tid];
        pr[tid] = f * ar[tid];
    }
    __syncthreads();
    if (tid < CNH) {
        float sl = 0.f, sr = 0.f;
        for (int c = 0; c < CNC; c++) {
            sl += pl[tid * CNC + c];
            sr += pr[tid * CNC + c];
        }
        el[n * CNH + tid] = sl;
        if (n < n_dst) er[n * CNH + tid] = sr;
    }
}

// ---------------- CSR build (both graphs per launch)
__global__ void hist2_kernel(const int* __restrict__ dst0, int* __restrict__ cnt0,
                             const int* __restrict__ dst1, int* __restrict__ cnt1) {
    int i = blockIdx.x * blockDim.x + threadIdx.x;
    if (i < CE0) {
        atomicAdd(&cnt0[dst0[i]], 1);
    } else {
        int j = i - CE0;
        if (j < CE1) atomicAdd(&cnt1[dst1[j]], 1);
    }
}

// per-1024-chunk scan; writes rp[i+1] (inclusive) and cur[i] (exclusive cursor)
__global__ __launch_bounds__(256) void scan1_kernel(const int* __restrict__ cnt0,
                                                    int* __restrict__ rp0, int* __restrict__ cur0,
                                                    int* __restrict__ bsums0, int nb0,
                                                    const int* __restrict__ cnt1,
                                                    int* __restrict__ rp1, int* __restrict__ cur1,
                                                    int* __restrict__ bsums1) {
    __shared__ int sm[256];
    int gb = blockIdx.x, tid = threadIdx.x;
    const int* cnt; int* rp; int* cur; int* bsums; int n; int b;
    if (gb < nb0) { cnt = cnt0; rp = rp0; cur = cur0; bsums = bsums0; n = CN1; b = gb; }
    else          { cnt = cnt1; rp = rp1; cur = cur1; bsums = bsums1; n = CN2; b = gb - nb0; }
    int base = b * 1024 + tid * 4;
    int v0 = 0, v1 = 0, v2 = 0, v3 = 0;
    if (base + 3 < n) {
        int4 q = *reinterpret_cast<const int4*>(&cnt[base]);
        v0 = q.x; v1 = q.y; v2 = q.z; v3 = q.w;
    } else {
        if (base + 0 < n) v0 = cnt[base + 0];
        if (base + 1 < n) v1 = cnt[base + 1];
        if (base + 2 < n) v2 = cnt[base + 2];
        if (base + 3 < n) v3 = cnt[base + 3];
    }
    int s1 = v0 + v1, s2 = s1 + v2, s3 = s2 + v3;
    sm[tid] = s3;
    __syncthreads();
    for (int off = 1; off < 256; off <<= 1) {
        int t = (tid >= off) ? sm[tid - off] : 0;
        __syncthreads();
        sm[tid] += t;
        __syncthreads();
    }
    int prefix = (tid > 0) ? sm[tid - 1] : 0;
    if (base + 0 < n) { rp[base + 1] = prefix + v0; cur[base + 0] = prefix; }
    if (base + 1 < n) { rp[base + 2] = prefix + s1; cur[base + 1] = prefix + v0; }
    if (base + 2 < n) { rp[base + 3] = prefix + s2; cur[base + 2] = prefix + s1; }
    if (base + 3 < n) { rp[base + 4] = prefix + s3; cur[base + 3] = prefix + s2; }
    if (tid == 255) bsums[b] = sm[255];
    if (b == 0 && tid == 0) rp[0] = 0;
}

__global__ __launch_bounds__(256) void scan2_kernel(int* __restrict__ bsums0, int nb0,
                                                    int* __restrict__ bsums1, int nb1) {
    __shared__ int sm[256];
    int tid = threadIdx.x;
    int* bsums = (blockIdx.x == 0) ? bsums0 : bsums1;
    int nb = (blockIdx.x == 0) ? nb0 : nb1;
    int v = (tid < nb) ? bsums[tid] : 0;
    sm[tid] = v;
    __syncthreads();
    for (int off = 1; off < 256; off <<= 1) {
        int t = (tid >= off) ? sm[tid - off] : 0;
        __syncthreads();
        sm[tid] += t;
        __syncthreads();
    }
    if (tid < nb) bsums[tid] = sm[tid] - v;  // exclusive
}

__global__ __launch_bounds__(256) void scan3_kernel(int* __restrict__ rp0, int* __restrict__ cur0,
                                                    const int* __restrict__ bsums0, int nb0,
                                                    int* __restrict__ rp1, int* __restrict__ cur1,
                                                    const int* __restrict__ bsums1) {
    int gb = blockIdx.x, tid = threadIdx.x;
    int* rp; int* cur; const int* bsums; int n; int b;
    if (gb < nb0) { rp = rp0; cur = cur0; bsums = bsums0; n = CN1; b = gb; }
    else          { rp = rp1; cur = cur1; bsums = bsums1; n = CN2; b = gb - nb0; }
    if (b == 0) return;
    int add = bsums[b];
    int idx = b * 1024 + tid * 4;
#pragma unroll
    for (int u = 0; u < 4; u++) {
        int p = idx + u;
        if (p < n) cur[p] += add;
        if (p + 1 <= n) rp[p + 1] += add;
    }
}

__global__ void scatter2_kernel(const int* __restrict__ dst0, const int* __restrict__ src0,
                                int* __restrict__ cur0, int* __restrict__ csr0,
                                const int* __restrict__ dst1, const int* __restrict__ src1,
                                int* __restrict__ cur1, int* __restrict__ csr1) {
    int i = blockIdx.x * blockDim.x + threadIdx.x;
    if (i < CE0) {
        int p = atomicAdd(&cur0[dst0[i]], 1);
        csr0[p] = src0[i];
    } else {
        int j = i - CE0;
        if (j < CE1) {
            int p = atomicAdd(&cur1[dst1[j]], 1);
            csr1[p] = src1[j];
        }
    }
}

// ---------------- per-edge alpha: one wave per dst node
__global__ __launch_bounds__(256) void alpha_kernel(const float* __restrict__ el,
                                                    const float* __restrict__ er,
                                                    const int* __restrict__ rp,
                                                    const int* __restrict__ csrsrc,
                                                    float* __restrict__ alpha, int n_dst) {
    int wid = (blockIdx.x * 256 + threadIdx.x) >> 6;
    int lane = threadIdx.x & 63;
    if (wid >= n_dst) return;
    int begin = rp[wid], end = rp[wid + 1];
    float4 erv = *reinterpret_cast<const float4*>(&er[wid * 4]);
    float m[4], s[4];
#pragma unroll
    for (int h = 0; h < 4; h++) { m[h] = -1e30f; s[h] = 0.f; }
    for (int i = begin + lane; i < end; i += 64) {
        int sn = csrsrc[i];
        float4 elv = *reinterpret_cast<const float4*>(&el[sn * 4]);
        float v[4] = {elv.x + erv.x, elv.y + erv.y, elv.z + erv.z, elv.w + erv.w};
#pragma unroll
        for (int h = 0; h < 4; h++) {
            float vv = v[h] > 0.f ? v[h] : 0.2f * v[h];
            float nm = fmaxf(m[h], vv);
            s[h] = s[h] * __expf(m[h] - nm) + __expf(vv - nm);
            m[h] = nm;
        }
    }
#pragma unroll
    for (int off = 1; off < 64; off <<= 1) {
#pragma unroll
        for (int h = 0; h < 4; h++) {
            float om = __shfl_xor(m[h], off);
            float os = __shfl_xor(s[h], off);
            float nm = fmaxf(m[h], om);
            s[h] = s[h] * __expf(m[h] - nm) + os * __expf(om - nm);
            m[h] = nm;
        }
    }
    float inv[4];
#pragma unroll
    for (int h = 0; h < 4; h++) inv[h] = s[h] > 0.f ? 1.f / s[h] : 0.f;
    for (int i = begin + lane; i < end; i += 64) {
        int sn = csrsrc[i];
        float4 elv = *reinterpret_cast<const float4*>(&el[sn * 4]);
        float v[4] = {elv.x + erv.x, elv.y + erv.y, elv.z + erv.z, elv.w + erv.w};
        float a[4];
#pragma unroll
        for (int h = 0; h < 4; h++) {
            float vv = v[h] > 0.f ? v[h] : 0.2f * v[h];
            a[h] = __expf(vv - m[h]) * inv[h];
        }
        *reinterpret_cast<float4*>(&alpha[(size_t)i * 4]) = make_float4(a[0], a[1], a[2], a[3]);
    }
}

// ---------------- layer-1 aggregation; emits h1 as bf16 hi/lo (pre-split for GEMM2)
#define CHUNK 128
__global__ __launch_bounds__(256) void agg1_kernel(const float* __restrict__ feat,
                                                   const float* __restrict__ alpha,
                                                   const int* __restrict__ rp,
                                                   const int* __restrict__ csrsrc,
                                                   const float* __restrict__ bias,
                                                   __bf16* __restrict__ h1h,
                                                   __bf16* __restrict__ h1l) {
    int dstn = blockIdx.x;
    int tid = threadIdx.x;
    int wave = tid >> 6, lane = tid & 63;
    __shared__ int s_src[CHUNK];
    __shared__ __align__(16) float s_alpha[CHUNK][4];
    __shared__ __align__(16) float s_red[3][256];
    int begin = rp[dstn], end = rp[dstn + 1];
    int head = lane >> 4;
    float4 acc = make_float4(0.f, 0.f, 0.f, 0.f);

    for (int cbase = begin; cbase < end; cbase += CHUNK) {
        int cn = min(end - cbase, CHUNK);
        for (int j = tid; j < cn; j += 256) {
            s_src[j] = csrsrc[cbase + j];
            *reinterpret_cast<float4*>(&s_alpha[j][0]) =
                *reinterpret_cast<const float4*>(&alpha[(size_t)(cbase + j) * 4]);
        }
        __syncthreads();
        for (int j = wave; j < cn; j += 4) {
            int sn = s_src[j];
            float a = s_alpha[j][head];
            float4 f = *reinterpret_cast<const float4*>(&feat[(size_t)sn * CHD1 + lane * 4]);
            acc.x += a * f.x; acc.y += a * f.y; acc.z += a * f.z; acc.w += a * f.w;
        }
        __syncthreads();
    }
    if (wave > 0) *reinterpret_cast<float4*>(&s_red[wave - 1][lane * 4]) = acc;
    __syncthreads();
    if (wave == 0) {
#pragma unroll
        for (int w = 0; w < 3; w++) {
            float4 o = *reinterpret_cast<float4*>(&s_red[w][lane * 4]);
            acc.x += o.x; acc.y += o.y; acc.z += o.z; acc.w += o.w;
        }
        float4 b = *reinterpret_cast<const float4*>(&bias[lane * 4]);
        float r[4] = {acc.x + b.x, acc.y + b.y, acc.z + b.z, acc.w + b.w};
        bf16x4 hv, lv;
#pragma unroll
        for (int u = 0; u < 4; u++) {
            float e = r[u] > 0.f ? r[u] : expm1f(r[u]);  // ELU
            __bf16 h = (__bf16)e;
            hv[u] = h;
            lv[u] = (__bf16)(e - (float)h);
        }
        *reinterpret_cast<bf16x4*>(&h1h[(size_t)dstn * CHD1 + lane * 4]) = hv;
        *reinterpret_cast<bf16x4*>(&h1l[(size_t)dstn * CHD1 + lane * 4]) = lv;
    }
}

// ---------------- layer-2 aggregation (fused head-mean)
__global__ __launch_bounds__(256) void agg2_kernel(const float* __restrict__ feat,
                                                   const float* __restrict__ alpha,
                                                   const int* __restrict__ rp,
                                                   const int* __restrict__ csrsrc,
                                                   const float* __restrict__ bias,
                                                   float* __restrict__ out) {
    int dstn = blockIdx.x;
    int tid = threadIdx.x;
    int wave = tid >> 6, lane = tid & 63;
    __shared__ int s_src[CHUNK];
    __shared__ __align__(16) float s_alpha[CHUNK][4];
    __shared__ float s_red[3][192];
    __shared__ float s_out[192];
    int begin = rp[dstn], end = rp[dstn + 1];
    int f0 = lane, f1 = lane + 64, f2 = lane + 128;
    int h0 = f0 / CNC, h1_ = f1 / CNC, h2 = f2 < CHC2 ? f2 / CNC : 3;
    float a0c = 0.f, a1c = 0.f, a2c = 0.f;

    for (int cbase = begin; cbase < end; cbase += CHUNK) {
        int cn = min(end - cbase, CHUNK);
        for (int j = tid; j < cn; j += 256) {
            s_src[j] = csrsrc[cbase + j];
            *reinterpret_cast<float4*>(&s_alpha[j][0]) =
                *reinterpret_cast<const float4*>(&alpha[(size_t)(cbase + j) * 4]);
        }
        __syncthreads();
        for (int j = wave; j < cn; j += 4) {
            int sn = s_src[j];
            const float* fr = &feat[(size_t)sn * CHC2];
            a0c += s_alpha[j][h0] * fr[f0];
            a1c += s_alpha[j][h1_] * fr[f1];
            if (f2 < CHC2) a2c += s_alpha[j][h2] * fr[f2];
        }
        __syncthreads();
    }
    if (wave > 0) {
        s_red[wave - 1][f0] = a0c;
        s_red[wave - 1][f1] = a1c;
        if (f2 < 192) s_red[wave - 1][f2] = a2c;
    }
    __syncthreads();
    if (wave == 0) {
#pragma unroll
        for (int w = 0; w < 3; w++) {
            a0c += s_red[w][f0];
            a1c += s_red[w][f1];
            if (f2 < 192) a2c += s_red[w][f2];
        }
        s_out[f0] = a0c + bias[f0];
        if (f1 < CHC2) s_out[f1] = a1c + bias[f1];
        if (f2 < CHC2) s_out[f2] = a2c + bias[f2];
    }
    __syncthreads();
    if (tid < CNC) {
        out[(size_t)dstn * CNC + tid] =
            0.25f * (s_out[tid] + s_out[CNC + tid] + s_out[2 * CNC + tid] + s_out[3 * CNC + tid]);
    }
}

extern "C" void kernel_launch(void* const* d_in, const int* in_sizes, int n_in,
                              void* d_out, int out_size, void* d_ws, size_t ws_size,
                              hipStream_t stream) {
    const float* x   = (const float*)d_in[0];
    const float* W1  = (const float*)d_in[1];
    const float* al1 = (const float*)d_in[2];
    const float* ar1 = (const float*)d_in[3];
    const float* b1  = (const float*)d_in[4];
    const float* W2  = (const float*)d_in[5];
    const float* al2 = (const float*)d_in[6];
    const float* ar2 = (const float*)d_in[7];
    const float* b2  = (const float*)d_in[8];
    const int* src0  = (const int*)d_in[9];
    const int* dst0  = (const int*)d_in[10];
    const int* src1  = (const int*)d_in[11];
    const int* dst1  = (const int*)d_in[12];
    float* out = (float*)d_out;

    char* base = (char*)d_ws;
    size_t off = 0;
    auto carve = [&](size_t bytes) {
        void* p = base + off;
        off = (off + bytes + 255) & ~(size_t)255;
        return p;
    };
    float* feat1   = (float*)carve((size_t)CN0 * CHD1 * 4);   // 102.4 MB; feat2 aliases
    __bf16* h1h    = (__bf16*)carve((size_t)CN1 * CHD1 * 2);  // 25.6 MB
    __bf16* h1l    = (__bf16*)carve((size_t)CN1 * CHD1 * 2);
    float* el1     = (float*)carve((size_t)CN0 * CNH * 4);
    float* er1     = (float*)carve((size_t)CN1 * CNH * 4);
    int* rp0       = (int*)carve((CN1 + 1) * 4);
    int* cnt0      = (int*)carve(CN1 * 4);                    // cnt0+cnt1 adjacent: 1 memset
    int* cnt1      = (int*)carve(CN2 * 4);
    int* csrsrc0   = (int*)carve((size_t)CE0 * 4);
    float* alpha0  = (float*)carve((size_t)CE0 * CNH * 4);    // 9.6 MB
    int* rp1       = (int*)carve((CN2 + 1) * 4);
    int* csrsrc1   = (int*)carve((size_t)CE1 * 4);
    float* alpha1  = (float*)carve((size_t)CE1 * CNH * 4);
    int* bsums0    = (int*)carve(64 * 4);
    int* bsums1    = (int*)carve(64 * 4);
    __bf16* W1Th   = (__bf16*)carve((size_t)CHD1 * CFIN * 2);
    __bf16* W1Tl   = (__bf16*)carve((size_t)CHD1 * CFIN * 2);
    __bf16* W2Th   = (__bf16*)carve((size_t)CHC2 * CHD1 * 2);
    __bf16* W2Tl   = (__bf16*)carve((size_t)CHC2 * CHD1 * 2);
    float* feat2 = feat1;  // feat1 dead after agg1
    float* el2 = el1;
    float* er2 = er1;

    const int LDS_BYTES = 2 * 4 * 128 * KP * 2;  // 81920
    hipFuncSetAttribute((const void*)gemm_mfma_kernel<true, true>,
                        hipFuncAttributeMaxDynamicSharedMemorySize, LDS_BYTES);
    hipFuncSetAttribute((const void*)gemm_mfma_kernel<false, false>,
                        hipFuncAttributeMaxDynamicSharedMemorySize, LDS_BYTES);

    // ---- weight prep (both layers, 1 launch)
    prep_w2_kernel<<<cdiv(CHD1 * CFIN + CHC2 * CHD1, 256), 256, 0, stream>>>(
        W1, W1Th, W1Tl, W2, W2Th, W2Tl);

    // ---- CSR builds (both graphs per launch; 6 ops total)
    hipMemsetAsync(cnt0, 0, (size_t)(CN1 + CN2 + 64) * 4, stream);  // covers cnt0+cnt1 (+pad)
    hist2_kernel<<<cdiv(CE0 + CE1, 256), 256, 0, stream>>>(dst0, cnt0, dst1, cnt1);
    int nb0 = cdiv(CN1, 1024), nb1 = cdiv(CN2, 1024);
    scan1_kernel<<<nb0 + nb1, 256, 0, stream>>>(cnt0, rp0, cnt0, bsums0, nb0,
                                                cnt1, rp1, cnt1, bsums1);
    scan2_kernel<<<2, 256, 0, stream>>>(bsums0, nb0, bsums1, nb1);
    scan3_kernel<<<nb0 + nb1, 256, 0, stream>>>(rp0, cnt0, bsums0, nb0, rp1, cnt1, bsums1);
    scatter2_kernel<<<cdiv(CE0 + CE1, 256), 256, 0, stream>>>(dst0, src0, cnt0, csrsrc0,
                                                              dst1, src1, cnt1, csrsrc1);

    // ---- layer 1 (scores fused into GEMM epilogue)
    gemm_mfma_kernel<true, true><<<dim3(cdiv(CN0, 128), cdiv(CHD1, 128)), 256, LDS_BYTES,
                                   stream>>>(x, nullptr, nullptr, W1Th, W1Tl, feat1,
                                             CN0, CHD1, CFIN, al1, ar1, el1, er1, CN1);
    alpha_kernel<<<cdiv(CN1, 4), 256, 0, stream>>>(el1, er1, rp0, csrsrc0, alpha0, CN1);
    agg1_kernel<<<CN1, 256, 0, stream>>>(feat1, alpha0, rp0, csrsrc0, b1, h1h, h1l);

    // ---- layer 2 (A pre-split by agg1; scores separate — heads don't align)
    gemm_mfma_kernel<false, false><<<dim3(cdiv(CN1, 128), cdiv(CHC2, 128)), 256, LDS_BYTES,
                                     stream>>>(nullptr, h1h, h1l, W2Th, W2Tl, feat2,
                                               CN1, CHC2, CHD1, nullptr, nullptr,
                                               nullptr, nullptr, 0);
    scores2_kernel<<<CN1, 192, 0, stream>>>(feat2, al2, ar2, el2, er2, CN2);
    alpha_kernel<<<cdiv(CN2, 4), 256, 0, stream>>>(el2, er2, rp1, csrsrc1, alpha1, CN2);
    agg2_kernel<<<CN2, 256, 0, stream>>>(feat2, alpha1, rp1, csrsrc1, b2, out);
}